// Round 6
// baseline (2529.115 us; speedup 1.0000x reference)
//
#include <hip/hip_runtime.h>

#define B_ 16
#define N_ 4096
#define S_ 1024
#define K_ 32
#define NSLOT 128
#define CNT_F 524288.0f   // B*S*K

// ---------------------------------------------------------------- FPS
// One block per batch. Distances in registers; xyz mirrored in LDS so the
// winning centroid is read by broadcast. Arithmetic matches np/jnp:
// ((dx*dx + dy*dy) + dz*dz), rn, no FMA contraction; first-index tie-break.
// Per iteration: wave shfl-reduce -> 8 leaders write packed u64 keys to
// DISTINCT double-buffered LDS slots (keys_s[s&1][wave]; no atomics, and the
// 2-deep rotation puts a barrier between any buffer's readers and its next
// writer) -> one barrier -> all threads reduce the 8 keys locally (scalar
// broadcast reads). No global stores in the loop.
#define FPS_T 512
#define FPS_P (N_ / FPS_T)
#define FPS_W (FPS_T / 64)

__global__ __launch_bounds__(FPS_T) void fps_kernel(
    const float* __restrict__ xyz, int* __restrict__ fps_idx,
    float* __restrict__ out_newxyz) {
  __shared__ float xyz_s[N_ * 3];                 // 48 KB
  __shared__ int idx_s[S_];                       // 4 KB
  __shared__ unsigned long long keys_s[2][FPS_W]; // 128 B
  int b = blockIdx.x, t = threadIdx.x;
  const float* xb = xyz + (size_t)b * N_ * 3;
  for (int i = t; i < N_ * 3; i += FPS_T) xyz_s[i] = xb[i];
  __syncthreads();
  float px[FPS_P], py[FPS_P], pz[FPS_P], dd[FPS_P];
#pragma unroll
  for (int j = 0; j < FPS_P; ++j) {
    int n = t + j * FPS_T;
    px[j] = xyz_s[n * 3 + 0];
    py[j] = xyz_s[n * 3 + 1];
    pz[j] = xyz_s[n * 3 + 2];
    dd[j] = 1e10f;
  }
  int fi = 0;
#pragma unroll 1
  for (int s = 0; s < S_; ++s) {
    if (t == 0) idx_s[s] = fi;
    float cx = xyz_s[fi * 3 + 0], cy = xyz_s[fi * 3 + 1], cz = xyz_s[fi * 3 + 2];
    float bv = -1.0f;
    int bi = 0;
#pragma unroll
    for (int j = 0; j < FPS_P; ++j) {
      float dx = __fsub_rn(px[j], cx);
      float dy = __fsub_rn(py[j], cy);
      float dz = __fsub_rn(pz[j], cz);
      float d = __fadd_rn(__fadd_rn(__fmul_rn(dx, dx), __fmul_rn(dy, dy)),
                          __fmul_rn(dz, dz));
      d = fminf(dd[j], d);
      dd[j] = d;
      if (d > bv) { bv = d; bi = t + j * FPS_T; }  // ascending n within lane
    }
#pragma unroll
    for (int off = 32; off > 0; off >>= 1) {
      float ov = __shfl_down(bv, off);
      int oi = __shfl_down(bi, off);
      if (ov > bv || (ov == bv && oi < bi)) { bv = ov; bi = oi; }
    }
    if ((t & 63) == 0) {
      // dist >= 0 so float bits are monotone; min-index tie-break via N-1-bi
      keys_s[s & 1][t >> 6] = ((unsigned long long)__float_as_uint(bv) << 32) |
                              (unsigned)(N_ - 1 - bi);
    }
    __syncthreads();
    // all threads redundantly reduce the 8 wave keys (broadcast reads)
    unsigned long long m = keys_s[s & 1][0];
#pragma unroll
    for (int w = 1; w < FPS_W; ++w) {
      unsigned long long k = keys_s[s & 1][w];
      m = k > m ? k : m;
    }
    fi = (N_ - 1) - (int)(unsigned)(m & 0xFFFFFFFFULL);
  }
  __syncthreads();
  for (int s = t; s < S_; s += FPS_T) {
    int i = idx_s[s];
    fps_idx[b * S_ + s] = i;
    out_newxyz[((size_t)b * S_ + s) * 3 + 0] = xyz_s[i * 3 + 0];
    out_newxyz[((size_t)b * S_ + s) * 3 + 1] = xyz_s[i * 3 + 1];
    out_newxyz[((size_t)b * S_ + s) * 3 + 2] = xyz_s[i * 3 + 2];
  }
}

// ---------------------------------------------------------------- point norms
__global__ void ptnorm_kernel(const float* __restrict__ xyz, float* __restrict__ pt) {
  int i = blockIdx.x * 256 + threadIdx.x;  // < B*N
  float x = xyz[(size_t)i * 3 + 0];
  float y = xyz[(size_t)i * 3 + 1];
  float z = xyz[(size_t)i * 3 + 2];
  pt[i] = __fadd_rn(__fadd_rn(__fmul_rn(x, x), __fmul_rn(y, y)), __fmul_rn(z, z));
}

// ---------------------------------------------------------------- kNN (K=32)
// One wave per (b,s). 32 passes of wave-argmin, lowest-index tie-break ==
// stable top_k set. Distances via the reference's norm expansion, matched rn.
__global__ __launch_bounds__(64) void knn_kernel(
    const float* __restrict__ xyz, const float* __restrict__ ptnorm,
    const float* __restrict__ newxyz, const int* __restrict__ fps_idx,
    int* __restrict__ nn_idx) {
  int bs = blockIdx.x;
  int b = bs >> 10;  // S=1024
  int lane = threadIdx.x;
  float sx = newxyz[(size_t)bs * 3 + 0];
  float sy = newxyz[(size_t)bs * 3 + 1];
  float sz = newxyz[(size_t)bs * 3 + 2];
  int fi = fps_idx[bs];
  float nxn = ptnorm[(size_t)b * N_ + fi];  // identical to ref's sum(src^2)
  const float* xb = xyz + (size_t)b * N_ * 3;
  const float* pnb = ptnorm + (size_t)b * N_;
  unsigned u[64];
#pragma unroll
  for (int j = 0; j < 64; ++j) {
    int n = j * 64 + lane;
    float x = xb[n * 3 + 0], y = xb[n * 3 + 1], z = xb[n * 3 + 2];
    float e = __fadd_rn(__fadd_rn(__fmul_rn(sx, x), __fmul_rn(sy, y)),
                        __fmul_rn(sz, z));
    float d = __fadd_rn(__fadd_rn(nxn, pnb[n]), __fmul_rn(-2.0f, e));
    int sb = __float_as_int(d);
    u[j] = (sb < 0) ? ~((unsigned)sb) : (((unsigned)sb) | 0x80000000u);
  }
  unsigned keep = 0;
#pragma unroll 1
  for (int p = 0; p < K_; ++p) {
    unsigned bv = 0xFFFFFFFFu;
    int bj = 0;
#pragma unroll
    for (int j = 0; j < 64; ++j) {
      if (u[j] < bv) { bv = u[j]; bj = j; }
    }
    unsigned bn = (unsigned)(bj * 64 + lane);
#pragma unroll
    for (int off = 32; off > 0; off >>= 1) {
      unsigned ov = __shfl_down(bv, off);
      unsigned on = __shfl_down(bn, off);
      if (ov < bv || (ov == bv && on < bn)) { bv = ov; bn = on; }
    }
    unsigned gn = __shfl(bn, 0);
    if (lane == p) keep = gn;
    if ((gn & 63u) == (unsigned)lane) {
      int gj = gn >> 6;
#pragma unroll
      for (int j = 0; j < 64; ++j)
        if (j == gj) u[j] = 0xFFFFFFFFu;
    }
  }
  if (lane < K_) nn_idx[(size_t)bs * K_ + lane] = (int)keep;
}

// ---------------------------------------------------------------- weight transpose
__global__ void prep_wT(const float* __restrict__ w0, const float* __restrict__ w1,
                        const float* __restrict__ w2, float* __restrict__ wT0,
                        float* __restrict__ wT1, float* __restrict__ wT2) {
  int t = blockIdx.x * 256 + threadIdx.x;
  if (t < 64 * 67) { int o = t / 67, c = t % 67; wT0[c * 64 + o] = w0[t]; }
  if (t < 64 * 64) { int o = t >> 6, c = t & 63; wT1[c * 64 + o] = w1[t]; }
  if (t < 128 * 64) { int o = t >> 6, c = t & 63; wT2[c * 128 + o] = w2[t]; }
}

// ---------------------------------------------------------------- stats helper
__device__ __forceinline__ void stats_accum(float acc[8][8], const float* __restrict__ bias_,
                                            int obase, int o0, int mq,
                                            float* __restrict__ stp) {
#pragma unroll
  for (int j = 0; j < 8; ++j) {
    float bv = bias_[obase + o0 + j];
    float s = 0.0f, q = 0.0f;
#pragma unroll
    for (int i = 0; i < 8; ++i) {
      float ya = acc[i][j] + bv;
      s += ya;
      q = fmaf(ya, ya, q);
    }
#pragma unroll
    for (int off = 1; off < 8; off <<= 1) {
      s += __shfl_xor(s, off);
      q += __shfl_xor(q, off);
    }
    if (mq == 0) {
      atomicAdd(&stp[(size_t)(obase + o0 + j) * 2 + 0], s);
      atomicAdd(&stp[(size_t)(obase + o0 + j) * 2 + 1], q);
    }
  }
}

// ---------------------------------------------------------------- fused layers
// One wave per 64 rows (= 2 s values x K=32). Gather feat into LDS (transposed
// [c][m]); chain GEMM0 -> bn0/relu -> GEMM1 -> bn1/relu -> GEMM2 through the
// SAME LDS buffer. PHASE 0: stats0 only. PHASE 1: +GEMM1, stats1. PHASE 2:
// full chain, stats2 + per-(s,o) max/min of raw y2 (pooling commutes with the
// BN affine). All math fp32.
template <int PHASE>
__global__ __launch_bounds__(64) void fused_layers(
    const float* __restrict__ xyz, const float* __restrict__ points,
    const float* __restrict__ newxyz, const int* __restrict__ nn_idx,
    const float* __restrict__ wT0, const float* __restrict__ bias0,
    const float* __restrict__ wT1, const float* __restrict__ bias1,
    const float* __restrict__ wT2, const float* __restrict__ bias2,
    const float* __restrict__ bnp,  // sc0@0 sh0@64 sc1@128 sh1@192
    float* __restrict__ stats, float* __restrict__ maxY, float* __restrict__ minY) {
  constexpr int MP = 68;
  __shared__ __align__(16) float xs[67 * MP];
  __shared__ int nn_s[64];
  __shared__ float nx_s[6];
  int t = threadIdx.x;
  int blk = blockIdx.x;
  int row0 = blk * 64;
  int b = blk >> 9;
  int s0 = (blk & 511) * 2;
  int bs0 = b * S_ + s0;
  nn_s[t] = nn_idx[row0 + t];
  if (t < 6) nx_s[t] = newxyz[(size_t)bs0 * 3 + t];
  __syncthreads();
  const float* xb = xyz + (size_t)b * N_ * 3;
  const float* pb = points + (size_t)b * N_ * 64;
#pragma unroll 4
  for (int m = 0; m < 64; ++m) {
    int idx = nn_s[m];
    if (t < 3) {
      xs[t * MP + m] = __fsub_rn(xb[idx * 3 + t], nx_s[(m >> 5) * 3 + t]);
      xs[(64 + t) * MP + m] = pb[(size_t)idx * 64 + 61 + t];
    } else {
      xs[t * MP + m] = pb[(size_t)idx * 64 + (t - 3)];
    }
  }
  __syncthreads();
  int mq = t & 7, oq = t >> 3;
  int m0 = mq * 8, o0 = oq * 8;
  float acc[8][8];
#pragma unroll
  for (int i = 0; i < 8; ++i)
#pragma unroll
    for (int j = 0; j < 8; ++j) acc[i][j] = 0.0f;
  // ---- GEMM0: [64 rows x 67 cin] x [67 x 64] ----
#pragma unroll 2
  for (int c = 0; c < 67; ++c) {
    float4 xa = *reinterpret_cast<const float4*>(&xs[c * MP + m0]);
    float4 xb4 = *reinterpret_cast<const float4*>(&xs[c * MP + m0 + 4]);
    float4 wa = *reinterpret_cast<const float4*>(&wT0[c * 64 + o0]);
    float4 wb = *reinterpret_cast<const float4*>(&wT0[c * 64 + o0 + 4]);
    float xr[8] = {xa.x, xa.y, xa.z, xa.w, xb4.x, xb4.y, xb4.z, xb4.w};
    float wr[8] = {wa.x, wa.y, wa.z, wa.w, wb.x, wb.y, wb.z, wb.w};
#pragma unroll
    for (int i = 0; i < 8; ++i)
#pragma unroll
      for (int j = 0; j < 8; ++j) acc[i][j] = fmaf(xr[i], wr[j], acc[i][j]);
  }
  if constexpr (PHASE == 0) {
    stats_accum(acc, bias0, 0, o0, mq, stats + (size_t)(blk & (NSLOT - 1)) * 64 * 2);
    return;
  } else {
    // x1 = relu(bn0(y0)) -> xs
    __syncthreads();  // all GEMM0 reads done
#pragma unroll
    for (int j = 0; j < 8; ++j) {
      float bv = bias0[o0 + j];
      float sc = bnp[o0 + j], sh = bnp[64 + o0 + j];
#pragma unroll
      for (int i = 0; i < 8; ++i) {
        float ya = acc[i][j] + bv;
        xs[(o0 + j) * MP + (m0 + i)] = fmaxf(fmaf(ya, sc, sh), 0.0f);
      }
    }
    __syncthreads();
    // ---- GEMM1: 64x64x64 ----
#pragma unroll
    for (int i = 0; i < 8; ++i)
#pragma unroll
      for (int j = 0; j < 8; ++j) acc[i][j] = 0.0f;
#pragma unroll 2
    for (int c = 0; c < 64; ++c) {
      float4 xa = *reinterpret_cast<const float4*>(&xs[c * MP + m0]);
      float4 xb4 = *reinterpret_cast<const float4*>(&xs[c * MP + m0 + 4]);
      float4 wa = *reinterpret_cast<const float4*>(&wT1[c * 64 + o0]);
      float4 wb = *reinterpret_cast<const float4*>(&wT1[c * 64 + o0 + 4]);
      float xr[8] = {xa.x, xa.y, xa.z, xa.w, xb4.x, xb4.y, xb4.z, xb4.w};
      float wr[8] = {wa.x, wa.y, wa.z, wa.w, wb.x, wb.y, wb.z, wb.w};
#pragma unroll
      for (int i = 0; i < 8; ++i)
#pragma unroll
        for (int j = 0; j < 8; ++j) acc[i][j] = fmaf(xr[i], wr[j], acc[i][j]);
    }
    if constexpr (PHASE == 1) {
      stats_accum(acc, bias1, 0, o0, mq, stats + (size_t)(blk & (NSLOT - 1)) * 64 * 2);
      return;
    } else {
      // x2 = relu(bn1(y1)) -> xs
      __syncthreads();
#pragma unroll
      for (int j = 0; j < 8; ++j) {
        float bv = bias1[o0 + j];
        float sc = bnp[128 + o0 + j], sh = bnp[192 + o0 + j];
#pragma unroll
        for (int i = 0; i < 8; ++i) {
          float ya = acc[i][j] + bv;
          xs[(o0 + j) * MP + (m0 + i)] = fmaxf(fmaf(ya, sc, sh), 0.0f);
        }
      }
      __syncthreads();
      // ---- GEMM2: 64x64x128, two o-halves ----
      float* stp = stats + (size_t)(blk & (NSLOT - 1)) * 128 * 2;
#pragma unroll 1
      for (int h = 0; h < 2; ++h) {
#pragma unroll
        for (int i = 0; i < 8; ++i)
#pragma unroll
          for (int j = 0; j < 8; ++j) acc[i][j] = 0.0f;
#pragma unroll 2
        for (int c = 0; c < 64; ++c) {
          float4 xa = *reinterpret_cast<const float4*>(&xs[c * MP + m0]);
          float4 xb4 = *reinterpret_cast<const float4*>(&xs[c * MP + m0 + 4]);
          float4 wa = *reinterpret_cast<const float4*>(&wT2[c * 128 + h * 64 + o0]);
          float4 wb = *reinterpret_cast<const float4*>(&wT2[c * 128 + h * 64 + o0 + 4]);
          float xr[8] = {xa.x, xa.y, xa.z, xa.w, xb4.x, xb4.y, xb4.z, xb4.w};
          float wr[8] = {wa.x, wa.y, wa.z, wa.w, wb.x, wb.y, wb.z, wb.w};
#pragma unroll
          for (int i = 0; i < 8; ++i)
#pragma unroll
            for (int j = 0; j < 8; ++j) acc[i][j] = fmaf(xr[i], wr[j], acc[i][j]);
        }
        stats_accum(acc, bias2, h * 64, o0, mq, stp);
        // per-(s,o) max/min of raw y2 over k (rows within this block)
#pragma unroll
        for (int j = 0; j < 8; ++j) {
          float bv = bias2[h * 64 + o0 + j];
          float mx = -3.4e38f, mn = 3.4e38f;
#pragma unroll
          for (int i = 0; i < 8; ++i) {
            float ya = acc[i][j] + bv;
            mx = fmaxf(mx, ya);
            mn = fminf(mn, ya);
          }
          mx = fmaxf(mx, __shfl_xor(mx, 1));
          mn = fminf(mn, __shfl_xor(mn, 1));
          mx = fmaxf(mx, __shfl_xor(mx, 2));
          mn = fminf(mn, __shfl_xor(mn, 2));
          if ((mq & 3) == 0) {
            size_t g = ((size_t)(bs0 + (mq >> 2))) * 128 + h * 64 + o0 + j;
            maxY[g] = mx;
            minY[g] = mn;
          }
        }
      }
    }
  }
}

// ---------------------------------------------------------------- BN finalize
__global__ void bn_finalize(const float* __restrict__ st, int cout,
                            const float* __restrict__ gamma,
                            const float* __restrict__ beta,
                            float* __restrict__ scale, float* __restrict__ shift) {
  int o = threadIdx.x;
  if (o >= cout) return;
  float s = 0.0f, q = 0.0f;
  for (int i = 0; i < NSLOT; ++i) {
    s += st[((size_t)i * cout + o) * 2 + 0];
    q += st[((size_t)i * cout + o) * 2 + 1];
  }
  float mean = s * (1.0f / CNT_F);
  float var = q * (1.0f / CNT_F) - mean * mean;
  float sc = gamma[o] / sqrtf(var + 1e-5f);
  scale[o] = sc;
  shift[o] = beta[o] - mean * sc;
}

// ---------------------------------------------------------------- pooling
// out[b,o,s] = relu(sc2*pick + sh2), pick = maxY if sc2>=0 else minY.
__global__ __launch_bounds__(256) void pool_kernel(
    const float* __restrict__ maxY, const float* __restrict__ minY,
    const float* __restrict__ bnp, float* __restrict__ out) {
  __shared__ float tile[128 * 65];
  int b = blockIdx.x >> 4;
  int sbase = (blockIdx.x & 15) * 64;
  int t = threadIdx.x;
#pragma unroll 4
  for (int i = 0; i < 32; ++i) {
    int e = i * 256 + t;  // 0..8191
    int sl = e >> 7, o = e & 127;
    float sc = bnp[256 + o], sh = bnp[384 + o];
    size_t g = ((size_t)(b * S_ + sbase + sl)) * 128 + o;
    float v = (sc >= 0.0f) ? maxY[g] : minY[g];
    tile[o * 65 + sl] = fmaxf(fmaf(v, sc, sh), 0.0f);
  }
  __syncthreads();
  int sl = t & 63;
  for (int o2 = t >> 6; o2 < 128; o2 += 4) {
    out[((size_t)(b * 128 + o2)) * S_ + sbase + sl] = tile[o2 * 65 + sl];
  }
}

// ---------------------------------------------------------------- launch
static inline size_t alup(size_t x) { return (x + 255) & ~(size_t)255; }

extern "C" void kernel_launch(void* const* d_in, const int* in_sizes, int n_in,
                              void* d_out, int out_size, void* d_ws, size_t ws_size,
                              hipStream_t stream) {
  (void)in_sizes; (void)n_in; (void)out_size;
  const float* xyz = (const float*)d_in[0];
  const float* points = (const float*)d_in[1];
  const float* w0 = (const float*)d_in[2];
  const float* b0 = (const float*)d_in[3];
  const float* g0 = (const float*)d_in[4];
  const float* be0 = (const float*)d_in[5];
  const float* w1 = (const float*)d_in[6];
  const float* b1 = (const float*)d_in[7];
  const float* g1 = (const float*)d_in[8];
  const float* be1 = (const float*)d_in[9];
  const float* w2 = (const float*)d_in[10];
  const float* b2 = (const float*)d_in[11];
  const float* g2 = (const float*)d_in[12];
  const float* be2 = (const float*)d_in[13];
  float* out_newxyz = (float*)d_out;
  float* out_newpts = out_newxyz + (size_t)B_ * S_ * 3;

  char* p = (char*)d_ws;
  int* fps = (int*)p;     p += alup((size_t)B_ * S_ * 4);
  int* nn = (int*)p;      p += alup((size_t)B_ * S_ * K_ * 4);
  float* ptn = (float*)p; p += alup((size_t)B_ * N_ * 4);
  float* st0 = (float*)p; p += (size_t)NSLOT * 64 * 2 * 4;
  float* st1 = (float*)p; p += (size_t)NSLOT * 64 * 2 * 4;
  float* st2 = (float*)p; p += (size_t)NSLOT * 128 * 2 * 4;
  float* bnp = (float*)p; p += alup(512 * 4);
  float* wT0 = (float*)p; p += alup(67 * 64 * 4);
  float* wT1 = (float*)p; p += alup(64 * 64 * 4);
  float* wT2 = (float*)p; p += alup(64 * 128 * 4);
  float* maxY = (float*)p; p += (size_t)B_ * S_ * 128 * 4;
  float* minY = (float*)p; p += (size_t)B_ * S_ * 128 * 4;
  if ((size_t)(p - (char*)d_ws) > ws_size) return;  // visible failure if ws too small

  float* sc0 = bnp;       float* sh0 = bnp + 64;
  float* sc1 = bnp + 128; float* sh1 = bnp + 192;
  float* sc2 = bnp + 256; float* sh2 = bnp + 384;

  hipMemsetAsync(st0, 0, (size_t)NSLOT * (64 + 64 + 128) * 2 * 4, stream);
  prep_wT<<<32, 256, 0, stream>>>(w0, w1, w2, wT0, wT1, wT2);
  ptnorm_kernel<<<(B_ * N_) / 256, 256, 0, stream>>>(xyz, ptn);
  fps_kernel<<<B_, FPS_T, 0, stream>>>(xyz, fps, out_newxyz);
  knn_kernel<<<B_ * S_, 64, 0, stream>>>(xyz, ptn, out_newxyz, fps, nn);
  fused_layers<0><<<(B_ * S_) / 2, 64, 0, stream>>>(
      xyz, points, out_newxyz, nn, wT0, b0, wT1, b1, wT2, b2, bnp, st0, maxY, minY);
  bn_finalize<<<1, 128, 0, stream>>>(st0, 64, g0, be0, sc0, sh0);
  fused_layers<1><<<(B_ * S_) / 2, 64, 0, stream>>>(
      xyz, points, out_newxyz, nn, wT0, b0, wT1, b1, wT2, b2, bnp, st1, maxY, minY);
  bn_finalize<<<1, 128, 0, stream>>>(st1, 64, g1, be1, sc1, sh1);
  fused_layers<2><<<(B_ * S_) / 2, 64, 0, stream>>>(
      xyz, points, out_newxyz, nn, wT0, b0, wT1, b1, wT2, b2, bnp, st2, maxY, minY);
  bn_finalize<<<1, 128, 0, stream>>>(st2, 128, g2, be2, sc2, sh2);
  pool_kernel<<<B_ * (S_ / 64), 256, 0, stream>>>(maxY, minY, bnp, out_newpts);
}

// Round 8
// 2164.765 us; speedup vs baseline: 1.1683x; 1.1683x over previous
//
#include <hip/hip_runtime.h>

#define B_ 16
#define N_ 4096
#define S_ 1024
#define K_ 32
#define NSLOT 128
#define CNT_F 524288.0f   // B*S*K

// ---------------------------------------------------------------- FPS
// One block per batch. Distances in registers; xyz mirrored in LDS so the
// winning centroid is read by broadcast. Arithmetic matches np/jnp:
// ((dx*dx + dy*dy) + dz*dz), rn, no FMA contraction; first-index tie-break.
// Wave reduce: packed u64 key (dist_bits<<32 | 4095-idx) reduced with a
// 6-level DPP max (VALU pipe, ~2-8 cyc/level) instead of ds_bpermute shfl
// (~120 cyc/level). Wave winner broadcast via readlane (sgpr). Cross-wave:
// 8 leaders write double-buffered LDS slots, 1 barrier, all threads reduce
// the 8 keys. No global stores in the loop.
#define FPS_T 512
#define FPS_P (N_ / FPS_T)
#define FPS_W (FPS_T / 64)

template <int CTRL>
__device__ __forceinline__ void dpp_max_u64(unsigned& hi, unsigned& lo) {
  unsigned h2 = (unsigned)__builtin_amdgcn_update_dpp(0, (int)hi, CTRL, 0xf, 0xf, true);
  unsigned l2 = (unsigned)__builtin_amdgcn_update_dpp(0, (int)lo, CTRL, 0xf, 0xf, true);
  bool take = (h2 > hi) || (h2 == hi && l2 > lo);
  hi = take ? h2 : hi;
  lo = take ? l2 : lo;
}

__global__ __launch_bounds__(FPS_T) void fps_kernel(
    const float* __restrict__ xyz, int* __restrict__ fps_idx,
    float* __restrict__ out_newxyz) {
  __shared__ float xyz_s[N_ * 3];                 // 48 KB
  __shared__ int idx_s[S_];                       // 4 KB
  __shared__ unsigned long long keys_s[2][FPS_W]; // 128 B
  int b = blockIdx.x, t = threadIdx.x;
  const float* xb = xyz + (size_t)b * N_ * 3;
  for (int i = t; i < N_ * 3; i += FPS_T) xyz_s[i] = xb[i];
  __syncthreads();
  float px[FPS_P], py[FPS_P], pz[FPS_P], dd[FPS_P];
#pragma unroll
  for (int j = 0; j < FPS_P; ++j) {
    int n = t + j * FPS_T;
    px[j] = xyz_s[n * 3 + 0];
    py[j] = xyz_s[n * 3 + 1];
    pz[j] = xyz_s[n * 3 + 2];
    dd[j] = 1e10f;
  }
  int fi = 0;
#pragma unroll 1
  for (int s = 0; s < S_; ++s) {
    if (t == 0) idx_s[s] = fi;
    float cx = xyz_s[fi * 3 + 0], cy = xyz_s[fi * 3 + 1], cz = xyz_s[fi * 3 + 2];
    float bv = -1.0f;
    int bi = 0;
#pragma unroll
    for (int j = 0; j < FPS_P; ++j) {
      float dx = __fsub_rn(px[j], cx);
      float dy = __fsub_rn(py[j], cy);
      float dz = __fsub_rn(pz[j], cz);
      float d = __fadd_rn(__fadd_rn(__fmul_rn(dx, dx), __fmul_rn(dy, dy)),
                          __fmul_rn(dz, dz));
      d = fminf(dd[j], d);
      dd[j] = d;
      if (d > bv) { bv = d; bi = t + j * FPS_T; }  // ascending n within lane
    }
    // pack: dist >= 0 so float bits are monotone; min-index tie via 4095-bi
    unsigned hi = __float_as_uint(bv);
    unsigned lo = (unsigned)(N_ - 1 - bi);
    // wave64 DPP max reduce (row_shr 1,2,4,8; row_bcast15; row_bcast31)
    dpp_max_u64<0x111>(hi, lo);
    dpp_max_u64<0x112>(hi, lo);
    dpp_max_u64<0x114>(hi, lo);
    dpp_max_u64<0x118>(hi, lo);
    dpp_max_u64<0x142>(hi, lo);
    dpp_max_u64<0x143>(hi, lo);
    // lane 63 holds the wave max; broadcast via readlane (uniform sgpr)
    unsigned whi = (unsigned)__builtin_amdgcn_readlane((int)hi, 63);
    unsigned wlo = (unsigned)__builtin_amdgcn_readlane((int)lo, 63);
    if ((t & 63) == 0)
      keys_s[s & 1][t >> 6] = ((unsigned long long)whi << 32) | wlo;
    __syncthreads();
    // all threads redundantly reduce the 8 wave keys (broadcast reads)
    unsigned long long m = keys_s[s & 1][0];
#pragma unroll
    for (int w = 1; w < FPS_W; ++w) {
      unsigned long long k = keys_s[s & 1][w];
      m = k > m ? k : m;
    }
    fi = (N_ - 1) - (int)(unsigned)(m & 0xFFFFFFFFULL);
  }
  __syncthreads();
  for (int s = t; s < S_; s += FPS_T) {
    int i = idx_s[s];
    fps_idx[b * S_ + s] = i;
    out_newxyz[((size_t)b * S_ + s) * 3 + 0] = xyz_s[i * 3 + 0];
    out_newxyz[((size_t)b * S_ + s) * 3 + 1] = xyz_s[i * 3 + 1];
    out_newxyz[((size_t)b * S_ + s) * 3 + 2] = xyz_s[i * 3 + 2];
  }
}

// ---------------------------------------------------------------- point norms
__global__ void ptnorm_kernel(const float* __restrict__ xyz, float* __restrict__ pt) {
  int i = blockIdx.x * 256 + threadIdx.x;  // < B*N
  float x = xyz[(size_t)i * 3 + 0];
  float y = xyz[(size_t)i * 3 + 1];
  float z = xyz[(size_t)i * 3 + 2];
  pt[i] = __fadd_rn(__fadd_rn(__fmul_rn(x, x), __fmul_rn(y, y)), __fmul_rn(z, z));
}

// ---------------------------------------------------------------- kNN (K=32)
// One wave per (b,s). 32 passes of wave-argmin, lowest-index tie-break ==
// stable top_k set. Distances via the reference's norm expansion, matched rn.
__global__ __launch_bounds__(64) void knn_kernel(
    const float* __restrict__ xyz, const float* __restrict__ ptnorm,
    const float* __restrict__ newxyz, const int* __restrict__ fps_idx,
    int* __restrict__ nn_idx) {
  int bs = blockIdx.x;
  int b = bs >> 10;  // S=1024
  int lane = threadIdx.x;
  float sx = newxyz[(size_t)bs * 3 + 0];
  float sy = newxyz[(size_t)bs * 3 + 1];
  float sz = newxyz[(size_t)bs * 3 + 2];
  int fi = fps_idx[bs];
  float nxn = ptnorm[(size_t)b * N_ + fi];  // identical to ref's sum(src^2)
  const float* xb = xyz + (size_t)b * N_ * 3;
  const float* pnb = ptnorm + (size_t)b * N_;
  unsigned u[64];
#pragma unroll
  for (int j = 0; j < 64; ++j) {
    int n = j * 64 + lane;
    float x = xb[n * 3 + 0], y = xb[n * 3 + 1], z = xb[n * 3 + 2];
    float e = __fadd_rn(__fadd_rn(__fmul_rn(sx, x), __fmul_rn(sy, y)),
                        __fmul_rn(sz, z));
    float d = __fadd_rn(__fadd_rn(nxn, pnb[n]), __fmul_rn(-2.0f, e));
    int sb = __float_as_int(d);
    u[j] = (sb < 0) ? ~((unsigned)sb) : (((unsigned)sb) | 0x80000000u);
  }
  unsigned keep = 0;
#pragma unroll 1
  for (int p = 0; p < K_; ++p) {
    unsigned bv = 0xFFFFFFFFu;
    int bj = 0;
#pragma unroll
    for (int j = 0; j < 64; ++j) {
      if (u[j] < bv) { bv = u[j]; bj = j; }
    }
    unsigned bn = (unsigned)(bj * 64 + lane);
#pragma unroll
    for (int off = 32; off > 0; off >>= 1) {
      unsigned ov = __shfl_down(bv, off);
      unsigned on = __shfl_down(bn, off);
      if (ov < bv || (ov == bv && on < bn)) { bv = ov; bn = on; }
    }
    unsigned gn = __shfl(bn, 0);
    if (lane == p) keep = gn;
    if ((gn & 63u) == (unsigned)lane) {
      int gj = gn >> 6;
#pragma unroll
      for (int j = 0; j < 64; ++j)
        if (j == gj) u[j] = 0xFFFFFFFFu;
    }
  }
  if (lane < K_) nn_idx[(size_t)bs * K_ + lane] = (int)keep;
}

// ---------------------------------------------------------------- weight transpose
__global__ void prep_wT(const float* __restrict__ w0, const float* __restrict__ w1,
                        const float* __restrict__ w2, float* __restrict__ wT0,
                        float* __restrict__ wT1, float* __restrict__ wT2) {
  int t = blockIdx.x * 256 + threadIdx.x;
  if (t < 64 * 67) { int o = t / 67, c = t % 67; wT0[c * 64 + o] = w0[t]; }
  if (t < 64 * 64) { int o = t >> 6, c = t & 63; wT1[c * 64 + o] = w1[t]; }
  if (t < 128 * 64) { int o = t >> 6, c = t & 63; wT2[c * 128 + o] = w2[t]; }
}

// ---------------------------------------------------------------- stats helper
__device__ __forceinline__ void stats_accum(float acc[8][8], const float* __restrict__ bias_,
                                            int obase, int o0, int mq,
                                            float* __restrict__ stp) {
#pragma unroll
  for (int j = 0; j < 8; ++j) {
    float bv = bias_[obase + o0 + j];
    float s = 0.0f, q = 0.0f;
#pragma unroll
    for (int i = 0; i < 8; ++i) {
      float ya = acc[i][j] + bv;
      s += ya;
      q = fmaf(ya, ya, q);
    }
#pragma unroll
    for (int off = 1; off < 8; off <<= 1) {
      s += __shfl_xor(s, off);
      q += __shfl_xor(q, off);
    }
    if (mq == 0) {
      atomicAdd(&stp[(size_t)(obase + o0 + j) * 2 + 0], s);
      atomicAdd(&stp[(size_t)(obase + o0 + j) * 2 + 1], q);
    }
  }
}

// ---------------------------------------------------------------- fused layers
// One wave per 64 rows (= 2 s values x K=32). Gather feat into LDS (transposed
// [c][m]); chain GEMM0 -> bn0/relu -> GEMM1 -> bn1/relu -> GEMM2 through the
// SAME LDS buffer. PHASE 0: stats0 only. PHASE 1: +GEMM1, stats1. PHASE 2:
// full chain, stats2 + per-(s,o) max/min of raw y2 (pooling commutes with the
// BN affine). All math fp32.
template <int PHASE>
__global__ __launch_bounds__(64) void fused_layers(
    const float* __restrict__ xyz, const float* __restrict__ points,
    const float* __restrict__ newxyz, const int* __restrict__ nn_idx,
    const float* __restrict__ wT0, const float* __restrict__ bias0,
    const float* __restrict__ wT1, const float* __restrict__ bias1,
    const float* __restrict__ wT2, const float* __restrict__ bias2,
    const float* __restrict__ bnp,  // sc0@0 sh0@64 sc1@128 sh1@192
    float* __restrict__ stats, float* __restrict__ maxY, float* __restrict__ minY) {
  constexpr int MP = 68;
  __shared__ __align__(16) float xs[67 * MP];
  __shared__ int nn_s[64];
  __shared__ float nx_s[6];
  int t = threadIdx.x;
  int blk = blockIdx.x;
  int row0 = blk * 64;
  int b = blk >> 9;
  int s0 = (blk & 511) * 2;
  int bs0 = b * S_ + s0;
  nn_s[t] = nn_idx[row0 + t];
  if (t < 6) nx_s[t] = newxyz[(size_t)bs0 * 3 + t];
  __syncthreads();
  const float* xb = xyz + (size_t)b * N_ * 3;
  const float* pb = points + (size_t)b * N_ * 64;
#pragma unroll 4
  for (int m = 0; m < 64; ++m) {
    int idx = nn_s[m];
    if (t < 3) {
      xs[t * MP + m] = __fsub_rn(xb[idx * 3 + t], nx_s[(m >> 5) * 3 + t]);
      xs[(64 + t) * MP + m] = pb[(size_t)idx * 64 + 61 + t];
    } else {
      xs[t * MP + m] = pb[(size_t)idx * 64 + (t - 3)];
    }
  }
  __syncthreads();
  int mq = t & 7, oq = t >> 3;
  int m0 = mq * 8, o0 = oq * 8;
  float acc[8][8];
#pragma unroll
  for (int i = 0; i < 8; ++i)
#pragma unroll
    for (int j = 0; j < 8; ++j) acc[i][j] = 0.0f;
  // ---- GEMM0: [64 rows x 67 cin] x [67 x 64] ----
#pragma unroll 2
  for (int c = 0; c < 67; ++c) {
    float4 xa = *reinterpret_cast<const float4*>(&xs[c * MP + m0]);
    float4 xb4 = *reinterpret_cast<const float4*>(&xs[c * MP + m0 + 4]);
    float4 wa = *reinterpret_cast<const float4*>(&wT0[c * 64 + o0]);
    float4 wb = *reinterpret_cast<const float4*>(&wT0[c * 64 + o0 + 4]);
    float xr[8] = {xa.x, xa.y, xa.z, xa.w, xb4.x, xb4.y, xb4.z, xb4.w};
    float wr[8] = {wa.x, wa.y, wa.z, wa.w, wb.x, wb.y, wb.z, wb.w};
#pragma unroll
    for (int i = 0; i < 8; ++i)
#pragma unroll
      for (int j = 0; j < 8; ++j) acc[i][j] = fmaf(xr[i], wr[j], acc[i][j]);
  }
  if constexpr (PHASE == 0) {
    stats_accum(acc, bias0, 0, o0, mq, stats + (size_t)(blk & (NSLOT - 1)) * 64 * 2);
    return;
  } else {
    // x1 = relu(bn0(y0)) -> xs
    __syncthreads();  // all GEMM0 reads done
#pragma unroll
    for (int j = 0; j < 8; ++j) {
      float bv = bias0[o0 + j];
      float sc = bnp[o0 + j], sh = bnp[64 + o0 + j];
#pragma unroll
      for (int i = 0; i < 8; ++i) {
        float ya = acc[i][j] + bv;
        xs[(o0 + j) * MP + (m0 + i)] = fmaxf(fmaf(ya, sc, sh), 0.0f);
      }
    }
    __syncthreads();
    // ---- GEMM1: 64x64x64 ----
#pragma unroll
    for (int i = 0; i < 8; ++i)
#pragma unroll
      for (int j = 0; j < 8; ++j) acc[i][j] = 0.0f;
#pragma unroll 2
    for (int c = 0; c < 64; ++c) {
      float4 xa = *reinterpret_cast<const float4*>(&xs[c * MP + m0]);
      float4 xb4 = *reinterpret_cast<const float4*>(&xs[c * MP + m0 + 4]);
      float4 wa = *reinterpret_cast<const float4*>(&wT1[c * 64 + o0]);
      float4 wb = *reinterpret_cast<const float4*>(&wT1[c * 64 + o0 + 4]);
      float xr[8] = {xa.x, xa.y, xa.z, xa.w, xb4.x, xb4.y, xb4.z, xb4.w};
      float wr[8] = {wa.x, wa.y, wa.z, wa.w, wb.x, wb.y, wb.z, wb.w};
#pragma unroll
      for (int i = 0; i < 8; ++i)
#pragma unroll
        for (int j = 0; j < 8; ++j) acc[i][j] = fmaf(xr[i], wr[j], acc[i][j]);
    }
    if constexpr (PHASE == 1) {
      stats_accum(acc, bias1, 0, o0, mq, stats + (size_t)(blk & (NSLOT - 1)) * 64 * 2);
      return;
    } else {
      // x2 = relu(bn1(y1)) -> xs
      __syncthreads();
#pragma unroll
      for (int j = 0; j < 8; ++j) {
        float bv = bias1[o0 + j];
        float sc = bnp[128 + o0 + j], sh = bnp[192 + o0 + j];
#pragma unroll
        for (int i = 0; i < 8; ++i) {
          float ya = acc[i][j] + bv;
          xs[(o0 + j) * MP + (m0 + i)] = fmaxf(fmaf(ya, sc, sh), 0.0f);
        }
      }
      __syncthreads();
      // ---- GEMM2: 64x64x128, two o-halves ----
      float* stp = stats + (size_t)(blk & (NSLOT - 1)) * 128 * 2;
#pragma unroll 1
      for (int h = 0; h < 2; ++h) {
#pragma unroll
        for (int i = 0; i < 8; ++i)
#pragma unroll
          for (int j = 0; j < 8; ++j) acc[i][j] = 0.0f;
#pragma unroll 2
        for (int c = 0; c < 64; ++c) {
          float4 xa = *reinterpret_cast<const float4*>(&xs[c * MP + m0]);
          float4 xb4 = *reinterpret_cast<const float4*>(&xs[c * MP + m0 + 4]);
          float4 wa = *reinterpret_cast<const float4*>(&wT2[c * 128 + h * 64 + o0]);
          float4 wb = *reinterpret_cast<const float4*>(&wT2[c * 128 + h * 64 + o0 + 4]);
          float xr[8] = {xa.x, xa.y, xa.z, xa.w, xb4.x, xb4.y, xb4.z, xb4.w};
          float wr[8] = {wa.x, wa.y, wa.z, wa.w, wb.x, wb.y, wb.z, wb.w};
#pragma unroll
          for (int i = 0; i < 8; ++i)
#pragma unroll
            for (int j = 0; j < 8; ++j) acc[i][j] = fmaf(xr[i], wr[j], acc[i][j]);
        }
        stats_accum(acc, bias2, h * 64, o0, mq, stp);
        // per-(s,o) max/min of raw y2 over k (rows within this block)
#pragma unroll
        for (int j = 0; j < 8; ++j) {
          float bv = bias2[h * 64 + o0 + j];
          float mx = -3.4e38f, mn = 3.4e38f;
#pragma unroll
          for (int i = 0; i < 8; ++i) {
            float ya = acc[i][j] + bv;
            mx = fmaxf(mx, ya);
            mn = fminf(mn, ya);
          }
          mx = fmaxf(mx, __shfl_xor(mx, 1));
          mn = fminf(mn, __shfl_xor(mn, 1));
          mx = fmaxf(mx, __shfl_xor(mx, 2));
          mn = fminf(mn, __shfl_xor(mn, 2));
          if ((mq & 3) == 0) {
            size_t g = ((size_t)(bs0 + (mq >> 2))) * 128 + h * 64 + o0 + j;
            maxY[g] = mx;
            minY[g] = mn;
          }
        }
      }
    }
  }
}

// ---------------------------------------------------------------- BN finalize
__global__ void bn_finalize(const float* __restrict__ st, int cout,
                            const float* __restrict__ gamma,
                            const float* __restrict__ beta,
                            float* __restrict__ scale, float* __restrict__ shift) {
  int o = threadIdx.x;
  if (o >= cout) return;
  float s = 0.0f, q = 0.0f;
  for (int i = 0; i < NSLOT; ++i) {
    s += st[((size_t)i * cout + o) * 2 + 0];
    q += st[((size_t)i * cout + o) * 2 + 1];
  }
  float mean = s * (1.0f / CNT_F);
  float var = q * (1.0f / CNT_F) - mean * mean;
  float sc = gamma[o] / sqrtf(var + 1e-5f);
  scale[o] = sc;
  shift[o] = beta[o] - mean * sc;
}

// ---------------------------------------------------------------- pooling
// out[b,o,s] = relu(sc2*pick + sh2), pick = maxY if sc2>=0 else minY.
__global__ __launch_bounds__(256) void pool_kernel(
    const float* __restrict__ maxY, const float* __restrict__ minY,
    const float* __restrict__ bnp, float* __restrict__ out) {
  __shared__ float tile[128 * 65];
  int b = blockIdx.x >> 4;
  int sbase = (blockIdx.x & 15) * 64;
  int t = threadIdx.x;
#pragma unroll 4
  for (int i = 0; i < 32; ++i) {
    int e = i * 256 + t;  // 0..8191
    int sl = e >> 7, o = e & 127;
    float sc = bnp[256 + o], sh = bnp[384 + o];
    size_t g = ((size_t)(b * S_ + sbase + sl)) * 128 + o;
    float v = (sc >= 0.0f) ? maxY[g] : minY[g];
    tile[o * 65 + sl] = fmaxf(fmaf(v, sc, sh), 0.0f);
  }
  __syncthreads();
  int sl = t & 63;
  for (int o2 = t >> 6; o2 < 128; o2 += 4) {
    out[((size_t)(b * 128 + o2)) * S_ + sbase + sl] = tile[o2 * 65 + sl];
  }
}

// ---------------------------------------------------------------- launch
static inline size_t alup(size_t x) { return (x + 255) & ~(size_t)255; }

extern "C" void kernel_launch(void* const* d_in, const int* in_sizes, int n_in,
                              void* d_out, int out_size, void* d_ws, size_t ws_size,
                              hipStream_t stream) {
  (void)in_sizes; (void)n_in; (void)out_size;
  const float* xyz = (const float*)d_in[0];
  const float* points = (const float*)d_in[1];
  const float* w0 = (const float*)d_in[2];
  const float* b0 = (const float*)d_in[3];
  const float* g0 = (const float*)d_in[4];
  const float* be0 = (const float*)d_in[5];
  const float* w1 = (const float*)d_in[6];
  const float* b1 = (const float*)d_in[7];
  const float* g1 = (const float*)d_in[8];
  const float* be1 = (const float*)d_in[9];
  const float* w2 = (const float*)d_in[10];
  const float* b2 = (const float*)d_in[11];
  const float* g2 = (const float*)d_in[12];
  const float* be2 = (const float*)d_in[13];
  float* out_newxyz = (float*)d_out;
  float* out_newpts = out_newxyz + (size_t)B_ * S_ * 3;

  char* p = (char*)d_ws;
  int* fps = (int*)p;     p += alup((size_t)B_ * S_ * 4);
  int* nn = (int*)p;      p += alup((size_t)B_ * S_ * K_ * 4);
  float* ptn = (float*)p; p += alup((size_t)B_ * N_ * 4);
  float* st0 = (float*)p; p += (size_t)NSLOT * 64 * 2 * 4;
  float* st1 = (float*)p; p += (size_t)NSLOT * 64 * 2 * 4;
  float* st2 = (float*)p; p += (size_t)NSLOT * 128 * 2 * 4;
  float* bnp = (float*)p; p += alup(512 * 4);
  float* wT0 = (float*)p; p += alup(67 * 64 * 4);
  float* wT1 = (float*)p; p += alup(64 * 64 * 4);
  float* wT2 = (float*)p; p += alup(64 * 128 * 4);
  float* maxY = (float*)p; p += (size_t)B_ * S_ * 128 * 4;
  float* minY = (float*)p; p += (size_t)B_ * S_ * 128 * 4;
  if ((size_t)(p - (char*)d_ws) > ws_size) return;  // visible failure if ws too small

  float* sc0 = bnp;       float* sh0 = bnp + 64;
  float* sc1 = bnp + 128; float* sh1 = bnp + 192;
  float* sc2 = bnp + 256; float* sh2 = bnp + 384;

  hipMemsetAsync(st0, 0, (size_t)NSLOT * (64 + 64 + 128) * 2 * 4, stream);
  prep_wT<<<32, 256, 0, stream>>>(w0, w1, w2, wT0, wT1, wT2);
  ptnorm_kernel<<<(B_ * N_) / 256, 256, 0, stream>>>(xyz, ptn);
  fps_kernel<<<B_, FPS_T, 0, stream>>>(xyz, fps, out_newxyz);
  knn_kernel<<<B_ * S_, 64, 0, stream>>>(xyz, ptn, out_newxyz, fps, nn);
  fused_layers<0><<<(B_ * S_) / 2, 64, 0, stream>>>(
      xyz, points, out_newxyz, nn, wT0, b0, wT1, b1, wT2, b2, bnp, st0, maxY, minY);
  bn_finalize<<<1, 128, 0, stream>>>(st0, 64, g0, be0, sc0, sh0);
  fused_layers<1><<<(B_ * S_) / 2, 64, 0, stream>>>(
      xyz, points, out_newxyz, nn, wT0, b0, wT1, b1, wT2, b2, bnp, st1, maxY, minY);
  bn_finalize<<<1, 128, 0, stream>>>(st1, 64, g1, be1, sc1, sh1);
  fused_layers<2><<<(B_ * S_) / 2, 64, 0, stream>>>(
      xyz, points, out_newxyz, nn, wT0, b0, wT1, b1, wT2, b2, bnp, st2, maxY, minY);
  bn_finalize<<<1, 128, 0, stream>>>(st2, 128, g2, be2, sc2, sh2);
  pool_kernel<<<B_ * (S_ / 64), 256, 0, stream>>>(maxY, minY, bnp, out_newpts);
}

// Round 9
// 1709.478 us; speedup vs baseline: 1.4795x; 1.2663x over previous
//
#include <hip/hip_runtime.h>

#define B_ 16
#define N_ 4096
#define S_ 1024
#define K_ 32
#define NSLOT 128
#define CNT_F 524288.0f   // B*S*K
#define RWS 524288        // total rows = B*S*K

typedef unsigned short ushort_t;

__device__ __forceinline__ ushort_t f2bf(float f) {
  unsigned u = __float_as_uint(f);
  unsigned r = (u + 0x7fffu + ((u >> 16) & 1u)) >> 16;
  return (ushort_t)r;
}

// ---------------------------------------------------------------- FPS
#define FPS_T 512
#define FPS_P (N_ / FPS_T)
#define FPS_W (FPS_T / 64)

template <int CTRL>
__device__ __forceinline__ void dpp_max_u64(unsigned& hi, unsigned& lo) {
  unsigned h2 = (unsigned)__builtin_amdgcn_update_dpp(0, (int)hi, CTRL, 0xf, 0xf, true);
  unsigned l2 = (unsigned)__builtin_amdgcn_update_dpp(0, (int)lo, CTRL, 0xf, 0xf, true);
  bool take = (h2 > hi) || (h2 == hi && l2 > lo);
  hi = take ? h2 : hi;
  lo = take ? l2 : lo;
}

__global__ __launch_bounds__(FPS_T) void fps_kernel(
    const float* __restrict__ xyz, int* __restrict__ fps_idx,
    float* __restrict__ out_newxyz) {
  __shared__ float xyz_s[N_ * 3];
  __shared__ int idx_s[S_];
  __shared__ unsigned long long keys_s[2][FPS_W];
  int b = blockIdx.x, t = threadIdx.x;
  const float* xb = xyz + (size_t)b * N_ * 3;
  for (int i = t; i < N_ * 3; i += FPS_T) xyz_s[i] = xb[i];
  __syncthreads();
  float px[FPS_P], py[FPS_P], pz[FPS_P], dd[FPS_P];
#pragma unroll
  for (int j = 0; j < FPS_P; ++j) {
    int n = t + j * FPS_T;
    px[j] = xyz_s[n * 3 + 0];
    py[j] = xyz_s[n * 3 + 1];
    pz[j] = xyz_s[n * 3 + 2];
    dd[j] = 1e10f;
  }
  int fi = 0;
#pragma unroll 1
  for (int s = 0; s < S_; ++s) {
    if (t == 0) idx_s[s] = fi;
    float cx = xyz_s[fi * 3 + 0], cy = xyz_s[fi * 3 + 1], cz = xyz_s[fi * 3 + 2];
    float bv = -1.0f;
    int bi = 0;
#pragma unroll
    for (int j = 0; j < FPS_P; ++j) {
      float dx = __fsub_rn(px[j], cx);
      float dy = __fsub_rn(py[j], cy);
      float dz = __fsub_rn(pz[j], cz);
      float d = __fadd_rn(__fadd_rn(__fmul_rn(dx, dx), __fmul_rn(dy, dy)),
                          __fmul_rn(dz, dz));
      d = fminf(dd[j], d);
      dd[j] = d;
      if (d > bv) { bv = d; bi = t + j * FPS_T; }
    }
    unsigned hi = __float_as_uint(bv);
    unsigned lo = (unsigned)(N_ - 1 - bi);
    dpp_max_u64<0x111>(hi, lo);
    dpp_max_u64<0x112>(hi, lo);
    dpp_max_u64<0x114>(hi, lo);
    dpp_max_u64<0x118>(hi, lo);
    dpp_max_u64<0x142>(hi, lo);
    dpp_max_u64<0x143>(hi, lo);
    unsigned whi = (unsigned)__builtin_amdgcn_readlane((int)hi, 63);
    unsigned wlo = (unsigned)__builtin_amdgcn_readlane((int)lo, 63);
    if ((t & 63) == 0)
      keys_s[s & 1][t >> 6] = ((unsigned long long)whi << 32) | wlo;
    __syncthreads();
    unsigned long long m = keys_s[s & 1][0];
#pragma unroll
    for (int w = 1; w < FPS_W; ++w) {
      unsigned long long k = keys_s[s & 1][w];
      m = k > m ? k : m;
    }
    fi = (N_ - 1) - (int)(unsigned)(m & 0xFFFFFFFFULL);
  }
  __syncthreads();
  for (int s = t; s < S_; s += FPS_T) {
    int i = idx_s[s];
    fps_idx[b * S_ + s] = i;
    out_newxyz[((size_t)b * S_ + s) * 3 + 0] = xyz_s[i * 3 + 0];
    out_newxyz[((size_t)b * S_ + s) * 3 + 1] = xyz_s[i * 3 + 1];
    out_newxyz[((size_t)b * S_ + s) * 3 + 2] = xyz_s[i * 3 + 2];
  }
}

// ---------------------------------------------------------------- point norms
__global__ void ptnorm_kernel(const float* __restrict__ xyz, float* __restrict__ pt) {
  int i = blockIdx.x * 256 + threadIdx.x;
  float x = xyz[(size_t)i * 3 + 0];
  float y = xyz[(size_t)i * 3 + 1];
  float z = xyz[(size_t)i * 3 + 2];
  pt[i] = __fadd_rn(__fadd_rn(__fmul_rn(x, x), __fmul_rn(y, y)), __fmul_rn(z, z));
}

// ---------------------------------------------------------------- kNN (K=32)
__global__ __launch_bounds__(64) void knn_kernel(
    const float* __restrict__ xyz, const float* __restrict__ ptnorm,
    const float* __restrict__ newxyz, const int* __restrict__ fps_idx,
    int* __restrict__ nn_idx) {
  int bs = blockIdx.x;
  int b = bs >> 10;
  int lane = threadIdx.x;
  float sx = newxyz[(size_t)bs * 3 + 0];
  float sy = newxyz[(size_t)bs * 3 + 1];
  float sz = newxyz[(size_t)bs * 3 + 2];
  int fi = fps_idx[bs];
  float nxn = ptnorm[(size_t)b * N_ + fi];
  const float* xb = xyz + (size_t)b * N_ * 3;
  const float* pnb = ptnorm + (size_t)b * N_;
  unsigned u[64];
#pragma unroll
  for (int j = 0; j < 64; ++j) {
    int n = j * 64 + lane;
    float x = xb[n * 3 + 0], y = xb[n * 3 + 1], z = xb[n * 3 + 2];
    float e = __fadd_rn(__fadd_rn(__fmul_rn(sx, x), __fmul_rn(sy, y)),
                        __fmul_rn(sz, z));
    float d = __fadd_rn(__fadd_rn(nxn, pnb[n]), __fmul_rn(-2.0f, e));
    int sb = __float_as_int(d);
    u[j] = (sb < 0) ? ~((unsigned)sb) : (((unsigned)sb) | 0x80000000u);
  }
  unsigned keep = 0;
#pragma unroll 1
  for (int p = 0; p < K_; ++p) {
    unsigned bv = 0xFFFFFFFFu;
    int bj = 0;
#pragma unroll
    for (int j = 0; j < 64; ++j) {
      if (u[j] < bv) { bv = u[j]; bj = j; }
    }
    unsigned bn = (unsigned)(bj * 64 + lane);
#pragma unroll
    for (int off = 32; off > 0; off >>= 1) {
      unsigned ov = __shfl_down(bv, off);
      unsigned on = __shfl_down(bn, off);
      if (ov < bv || (ov == bv && on < bn)) { bv = ov; bn = on; }
    }
    unsigned gn = __shfl(bn, 0);
    if (lane == p) keep = gn;
    if ((gn & 63u) == (unsigned)lane) {
      int gj = gn >> 6;
#pragma unroll
      for (int j = 0; j < 64; ++j)
        if (j == gj) u[j] = 0xFFFFFFFFu;
    }
  }
  if (lane < K_) nn_idx[(size_t)bs * K_ + lane] = (int)keep;
}

// ---------------------------------------------------------------- weight transpose
__global__ void prep_wT(const float* __restrict__ w0, const float* __restrict__ w1,
                        const float* __restrict__ w2, float* __restrict__ wT0,
                        float* __restrict__ wT1, float* __restrict__ wT2) {
  int t = blockIdx.x * 256 + threadIdx.x;
  if (t < 64 * 67) { int o = t / 67, c = t % 67; wT0[c * 64 + o] = w0[t]; }
  if (t < 64 * 64) { int o = t >> 6, c = t & 63; wT1[c * 64 + o] = w1[t]; }
  if (t < 128 * 64) { int o = t >> 6, c = t & 63; wT2[c * 128 + o] = w2[t]; }
}

// ---------------------------------------------------------------- stats helper
__device__ __forceinline__ void stats_accum(float acc[8][8], const float* __restrict__ bias_,
                                            int obase, int o0, int mq,
                                            float* __restrict__ stp) {
#pragma unroll
  for (int j = 0; j < 8; ++j) {
    float bv = bias_[obase + o0 + j];
    float s = 0.0f, q = 0.0f;
#pragma unroll
    for (int i = 0; i < 8; ++i) {
      float ya = acc[i][j] + bv;
      s += ya;
      q = fmaf(ya, ya, q);
    }
#pragma unroll
    for (int off = 1; off < 8; off <<= 1) {
      s += __shfl_xor(s, off);
      q += __shfl_xor(q, off);
    }
    if (mq == 0) {
      atomicAdd(&stp[(size_t)(obase + o0 + j) * 2 + 0], s);
      atomicAdd(&stp[(size_t)(obase + o0 + j) * 2 + 1], q);
    }
  }
}

// ================================================================ FULL path
// Phase A: conflict-free gather (lane = row), GEMM0, store raw y0 bf16
// transposed [c][row], stats0.
__global__ __launch_bounds__(64) void gemm0_mat(
    const float* __restrict__ xyz, const float* __restrict__ points,
    const float* __restrict__ newxyz, const int* __restrict__ nn_idx,
    const float* __restrict__ wT0, const float* __restrict__ bias0,
    ushort_t* __restrict__ y0T, float* __restrict__ stats) {
  constexpr int MP = 68;
  __shared__ __align__(16) float xs[67 * MP];
  int t = threadIdx.x;
  int blk = blockIdx.x;
  int row0 = blk * 64;
  int b = blk >> 9;
  int s0 = (blk & 511) * 2;
  int bs0 = b * S_ + s0;
  int idx = nn_idx[row0 + t];
  const float* xb = xyz + (size_t)b * N_ * 3;
  const float4* pb4 = reinterpret_cast<const float4*>(
      points + (size_t)b * N_ * 64 + (size_t)idx * 64);
  int sh = t >> 5;  // which of the 2 s values this row belongs to
  float nx0 = newxyz[(size_t)(bs0 + sh) * 3 + 0];
  float nx1 = newxyz[(size_t)(bs0 + sh) * 3 + 1];
  float nx2 = newxyz[(size_t)(bs0 + sh) * 3 + 2];
  // rows 3..66 = points channels (conflict-free: lane-contiguous writes)
#pragma unroll
  for (int q = 0; q < 16; ++q) {
    float4 v = pb4[q];
    xs[(3 + 4 * q + 0) * MP + t] = v.x;
    xs[(3 + 4 * q + 1) * MP + t] = v.y;
    xs[(3 + 4 * q + 2) * MP + t] = v.z;
    xs[(3 + 4 * q + 3) * MP + t] = v.w;
  }
  xs[0 * MP + t] = __fsub_rn(xb[idx * 3 + 0], nx0);
  xs[1 * MP + t] = __fsub_rn(xb[idx * 3 + 1], nx1);
  xs[2 * MP + t] = __fsub_rn(xb[idx * 3 + 2], nx2);
  __syncthreads();
  int mq = t & 7, oq = t >> 3;
  int m0 = mq * 8, o0 = oq * 8;
  float acc[8][8];
#pragma unroll
  for (int i = 0; i < 8; ++i)
#pragma unroll
    for (int j = 0; j < 8; ++j) acc[i][j] = 0.0f;
#pragma unroll 2
  for (int c = 0; c < 67; ++c) {
    float4 xa = *reinterpret_cast<const float4*>(&xs[c * MP + m0]);
    float4 xb4 = *reinterpret_cast<const float4*>(&xs[c * MP + m0 + 4]);
    float4 wa = *reinterpret_cast<const float4*>(&wT0[c * 64 + o0]);
    float4 wb = *reinterpret_cast<const float4*>(&wT0[c * 64 + o0 + 4]);
    float xr[8] = {xa.x, xa.y, xa.z, xa.w, xb4.x, xb4.y, xb4.z, xb4.w};
    float wr[8] = {wa.x, wa.y, wa.z, wa.w, wb.x, wb.y, wb.z, wb.w};
#pragma unroll
    for (int i = 0; i < 8; ++i)
#pragma unroll
      for (int j = 0; j < 8; ++j) acc[i][j] = fmaf(xr[i], wr[j], acc[i][j]);
  }
  // store y0 (raw conv+bias) as bf16, transposed [o][row]
  ushort_t* yo = y0T + row0 + m0;
#pragma unroll
  for (int j = 0; j < 8; ++j) {
    float bv = bias0[o0 + j];
    unsigned pk[4];
#pragma unroll
    for (int ii = 0; ii < 4; ++ii) {
      float a = acc[2 * ii][j] + bv;
      float c2 = acc[2 * ii + 1][j] + bv;
      pk[ii] = (unsigned)f2bf(a) | ((unsigned)f2bf(c2) << 16);
    }
    *reinterpret_cast<uint4*>(yo + (size_t)(o0 + j) * RWS) =
        make_uint4(pk[0], pk[1], pk[2], pk[3]);
  }
  stats_accum(acc, bias0, 0, o0, mq, stats + (size_t)(blk & (NSLOT - 1)) * 64 * 2);
}

// Phase B: stream y0T, bn0/relu inline, GEMM1, store y1T bf16, stats1.
// No LDS, no barrier.
__global__ __launch_bounds__(64) void gemm1_mat(
    const ushort_t* __restrict__ y0T, const float* __restrict__ bnp,
    const float* __restrict__ wT1, const float* __restrict__ bias1,
    ushort_t* __restrict__ y1T, float* __restrict__ stats) {
  int t = threadIdx.x;
  int blk = blockIdx.x;
  int row0 = blk * 64;
  int mq = t & 7, oq = t >> 3;
  int m0 = mq * 8, o0 = oq * 8;
  float acc[8][8];
#pragma unroll
  for (int i = 0; i < 8; ++i)
#pragma unroll
    for (int j = 0; j < 8; ++j) acc[i][j] = 0.0f;
  const ushort_t* xbase = y0T + row0 + m0;
#pragma unroll 2
  for (int c = 0; c < 64; ++c) {
    uint4 xv = *reinterpret_cast<const uint4*>(xbase + (size_t)c * RWS);
    float sc = bnp[c], sh = bnp[64 + c];
    float xr[8];
    xr[0] = __uint_as_float(xv.x << 16);
    xr[1] = __uint_as_float(xv.x & 0xffff0000u);
    xr[2] = __uint_as_float(xv.y << 16);
    xr[3] = __uint_as_float(xv.y & 0xffff0000u);
    xr[4] = __uint_as_float(xv.z << 16);
    xr[5] = __uint_as_float(xv.z & 0xffff0000u);
    xr[6] = __uint_as_float(xv.w << 16);
    xr[7] = __uint_as_float(xv.w & 0xffff0000u);
#pragma unroll
    for (int i = 0; i < 8; ++i) xr[i] = fmaxf(fmaf(xr[i], sc, sh), 0.0f);
    float4 wa = *reinterpret_cast<const float4*>(&wT1[c * 64 + o0]);
    float4 wb = *reinterpret_cast<const float4*>(&wT1[c * 64 + o0 + 4]);
    float wr[8] = {wa.x, wa.y, wa.z, wa.w, wb.x, wb.y, wb.z, wb.w};
#pragma unroll
    for (int i = 0; i < 8; ++i)
#pragma unroll
      for (int j = 0; j < 8; ++j) acc[i][j] = fmaf(xr[i], wr[j], acc[i][j]);
  }
  ushort_t* yo = y1T + row0 + m0;
#pragma unroll
  for (int j = 0; j < 8; ++j) {
    float bv = bias1[o0 + j];
    unsigned pk[4];
#pragma unroll
    for (int ii = 0; ii < 4; ++ii) {
      float a = acc[2 * ii][j] + bv;
      float c2 = acc[2 * ii + 1][j] + bv;
      pk[ii] = (unsigned)f2bf(a) | ((unsigned)f2bf(c2) << 16);
    }
    *reinterpret_cast<uint4*>(yo + (size_t)(o0 + j) * RWS) =
        make_uint4(pk[0], pk[1], pk[2], pk[3]);
  }
  stats_accum(acc, bias1, 0, o0, mq, stats + (size_t)(blk & (NSLOT - 1)) * 64 * 2);
}

// Phase C: stream y1T, bn1/relu inline, GEMM2 (2 halves), stats2 + min/max.
__global__ __launch_bounds__(64) void gemm2_mat(
    const ushort_t* __restrict__ y1T, const float* __restrict__ bnp,
    const float* __restrict__ wT2, const float* __restrict__ bias2,
    float* __restrict__ stats, float* __restrict__ maxY, float* __restrict__ minY) {
  int t = threadIdx.x;
  int blk = blockIdx.x;
  int row0 = blk * 64;
  int b = blk >> 9;
  int s0 = (blk & 511) * 2;
  int bs0 = b * S_ + s0;
  int mq = t & 7, oq = t >> 3;
  int m0 = mq * 8, o0 = oq * 8;
  const ushort_t* xbase = y1T + row0 + m0;
  float* stp = stats + (size_t)(blk & (NSLOT - 1)) * 128 * 2;
#pragma unroll 1
  for (int h = 0; h < 2; ++h) {
    float acc[8][8];
#pragma unroll
    for (int i = 0; i < 8; ++i)
#pragma unroll
      for (int j = 0; j < 8; ++j) acc[i][j] = 0.0f;
#pragma unroll 2
    for (int c = 0; c < 64; ++c) {
      uint4 xv = *reinterpret_cast<const uint4*>(xbase + (size_t)c * RWS);
      float sc = bnp[128 + c], sh = bnp[192 + c];
      float xr[8];
      xr[0] = __uint_as_float(xv.x << 16);
      xr[1] = __uint_as_float(xv.x & 0xffff0000u);
      xr[2] = __uint_as_float(xv.y << 16);
      xr[3] = __uint_as_float(xv.y & 0xffff0000u);
      xr[4] = __uint_as_float(xv.z << 16);
      xr[5] = __uint_as_float(xv.z & 0xffff0000u);
      xr[6] = __uint_as_float(xv.w << 16);
      xr[7] = __uint_as_float(xv.w & 0xffff0000u);
#pragma unroll
      for (int i = 0; i < 8; ++i) xr[i] = fmaxf(fmaf(xr[i], sc, sh), 0.0f);
      float4 wa = *reinterpret_cast<const float4*>(&wT2[c * 128 + h * 64 + o0]);
      float4 wb = *reinterpret_cast<const float4*>(&wT2[c * 128 + h * 64 + o0 + 4]);
      float wr[8] = {wa.x, wa.y, wa.z, wa.w, wb.x, wb.y, wb.z, wb.w};
#pragma unroll
      for (int i = 0; i < 8; ++i)
#pragma unroll
        for (int j = 0; j < 8; ++j) acc[i][j] = fmaf(xr[i], wr[j], acc[i][j]);
    }
    stats_accum(acc, bias2, h * 64, o0, mq, stp);
#pragma unroll
    for (int j = 0; j < 8; ++j) {
      float bv = bias2[h * 64 + o0 + j];
      float mx = -3.4e38f, mn = 3.4e38f;
#pragma unroll
      for (int i = 0; i < 8; ++i) {
        float ya = acc[i][j] + bv;
        mx = fmaxf(mx, ya);
        mn = fminf(mn, ya);
      }
      mx = fmaxf(mx, __shfl_xor(mx, 1));
      mn = fminf(mn, __shfl_xor(mn, 1));
      mx = fmaxf(mx, __shfl_xor(mx, 2));
      mn = fminf(mn, __shfl_xor(mn, 2));
      if ((mq & 3) == 0) {
        size_t g = ((size_t)(bs0 + (mq >> 2))) * 128 + h * 64 + o0 + j;
        maxY[g] = mx;
        minY[g] = mn;
      }
    }
  }
}

// ================================================================ legacy path
template <int PHASE>
__global__ __launch_bounds__(64) void fused_layers(
    const float* __restrict__ xyz, const float* __restrict__ points,
    const float* __restrict__ newxyz, const int* __restrict__ nn_idx,
    const float* __restrict__ wT0, const float* __restrict__ bias0,
    const float* __restrict__ wT1, const float* __restrict__ bias1,
    const float* __restrict__ wT2, const float* __restrict__ bias2,
    const float* __restrict__ bnp,
    float* __restrict__ stats, float* __restrict__ maxY, float* __restrict__ minY) {
  constexpr int MP = 68;
  __shared__ __align__(16) float xs[67 * MP];
  __shared__ int nn_s[64];
  __shared__ float nx_s[6];
  int t = threadIdx.x;
  int blk = blockIdx.x;
  int row0 = blk * 64;
  int b = blk >> 9;
  int s0 = (blk & 511) * 2;
  int bs0 = b * S_ + s0;
  nn_s[t] = nn_idx[row0 + t];
  if (t < 6) nx_s[t] = newxyz[(size_t)bs0 * 3 + t];
  __syncthreads();
  const float* xb = xyz + (size_t)b * N_ * 3;
  const float* pb = points + (size_t)b * N_ * 64;
#pragma unroll 4
  for (int m = 0; m < 64; ++m) {
    int idx = nn_s[m];
    if (t < 3) {
      xs[t * MP + m] = __fsub_rn(xb[idx * 3 + t], nx_s[(m >> 5) * 3 + t]);
      xs[(64 + t) * MP + m] = pb[(size_t)idx * 64 + 61 + t];
    } else {
      xs[t * MP + m] = pb[(size_t)idx * 64 + (t - 3)];
    }
  }
  __syncthreads();
  int mq = t & 7, oq = t >> 3;
  int m0 = mq * 8, o0 = oq * 8;
  float acc[8][8];
#pragma unroll
  for (int i = 0; i < 8; ++i)
#pragma unroll
    for (int j = 0; j < 8; ++j) acc[i][j] = 0.0f;
#pragma unroll 2
  for (int c = 0; c < 67; ++c) {
    float4 xa = *reinterpret_cast<const float4*>(&xs[c * MP + m0]);
    float4 xb4 = *reinterpret_cast<const float4*>(&xs[c * MP + m0 + 4]);
    float4 wa = *reinterpret_cast<const float4*>(&wT0[c * 64 + o0]);
    float4 wb = *reinterpret_cast<const float4*>(&wT0[c * 64 + o0 + 4]);
    float xr[8] = {xa.x, xa.y, xa.z, xa.w, xb4.x, xb4.y, xb4.z, xb4.w};
    float wr[8] = {wa.x, wa.y, wa.z, wa.w, wb.x, wb.y, wb.z, wb.w};
#pragma unroll
    for (int i = 0; i < 8; ++i)
#pragma unroll
      for (int j = 0; j < 8; ++j) acc[i][j] = fmaf(xr[i], wr[j], acc[i][j]);
  }
  if constexpr (PHASE == 0) {
    stats_accum(acc, bias0, 0, o0, mq, stats + (size_t)(blk & (NSLOT - 1)) * 64 * 2);
    return;
  } else {
    __syncthreads();
#pragma unroll
    for (int j = 0; j < 8; ++j) {
      float bv = bias0[o0 + j];
      float sc = bnp[o0 + j], sh = bnp[64 + o0 + j];
#pragma unroll
      for (int i = 0; i < 8; ++i) {
        float ya = acc[i][j] + bv;
        xs[(o0 + j) * MP + (m0 + i)] = fmaxf(fmaf(ya, sc, sh), 0.0f);
      }
    }
    __syncthreads();
#pragma unroll
    for (int i = 0; i < 8; ++i)
#pragma unroll
      for (int j = 0; j < 8; ++j) acc[i][j] = 0.0f;
#pragma unroll 2
    for (int c = 0; c < 64; ++c) {
      float4 xa = *reinterpret_cast<const float4*>(&xs[c * MP + m0]);
      float4 xb4 = *reinterpret_cast<const float4*>(&xs[c * MP + m0 + 4]);
      float4 wa = *reinterpret_cast<const float4*>(&wT1[c * 64 + o0]);
      float4 wb = *reinterpret_cast<const float4*>(&wT1[c * 64 + o0 + 4]);
      float xr[8] = {xa.x, xa.y, xa.z, xa.w, xb4.x, xb4.y, xb4.z, xb4.w};
      float wr[8] = {wa.x, wa.y, wa.z, wa.w, wb.x, wb.y, wb.z, wb.w};
#pragma unroll
      for (int i = 0; i < 8; ++i)
#pragma unroll
        for (int j = 0; j < 8; ++j) acc[i][j] = fmaf(xr[i], wr[j], acc[i][j]);
    }
    if constexpr (PHASE == 1) {
      stats_accum(acc, bias1, 0, o0, mq, stats + (size_t)(blk & (NSLOT - 1)) * 64 * 2);
      return;
    } else {
      __syncthreads();
#pragma unroll
      for (int j = 0; j < 8; ++j) {
        float bv = bias1[o0 + j];
        float sc = bnp[128 + o0 + j], sh = bnp[192 + o0 + j];
#pragma unroll
        for (int i = 0; i < 8; ++i) {
          float ya = acc[i][j] + bv;
          xs[(o0 + j) * MP + (m0 + i)] = fmaxf(fmaf(ya, sc, sh), 0.0f);
        }
      }
      __syncthreads();
      float* stp = stats + (size_t)(blk & (NSLOT - 1)) * 128 * 2;
#pragma unroll 1
      for (int h = 0; h < 2; ++h) {
#pragma unroll
        for (int i = 0; i < 8; ++i)
#pragma unroll
          for (int j = 0; j < 8; ++j) acc[i][j] = 0.0f;
#pragma unroll 2
        for (int c = 0; c < 64; ++c) {
          float4 xa = *reinterpret_cast<const float4*>(&xs[c * MP + m0]);
          float4 xb4 = *reinterpret_cast<const float4*>(&xs[c * MP + m0 + 4]);
          float4 wa = *reinterpret_cast<const float4*>(&wT2[c * 128 + h * 64 + o0]);
          float4 wb = *reinterpret_cast<const float4*>(&wT2[c * 128 + h * 64 + o0 + 4]);
          float xr[8] = {xa.x, xa.y, xa.z, xa.w, xb4.x, xb4.y, xb4.z, xb4.w};
          float wr[8] = {wa.x, wa.y, wa.z, wa.w, wb.x, wb.y, wb.z, wb.w};
#pragma unroll
          for (int i = 0; i < 8; ++i)
#pragma unroll
            for (int j = 0; j < 8; ++j) acc[i][j] = fmaf(xr[i], wr[j], acc[i][j]);
        }
        stats_accum(acc, bias2, h * 64, o0, mq, stp);
#pragma unroll
        for (int j = 0; j < 8; ++j) {
          float bv = bias2[h * 64 + o0 + j];
          float mx = -3.4e38f, mn = 3.4e38f;
#pragma unroll
          for (int i = 0; i < 8; ++i) {
            float ya = acc[i][j] + bv;
            mx = fmaxf(mx, ya);
            mn = fminf(mn, ya);
          }
          mx = fmaxf(mx, __shfl_xor(mx, 1));
          mn = fminf(mn, __shfl_xor(mn, 1));
          mx = fmaxf(mx, __shfl_xor(mx, 2));
          mn = fminf(mn, __shfl_xor(mn, 2));
          if ((mq & 3) == 0) {
            size_t g = ((size_t)(bs0 + (mq >> 2))) * 128 + h * 64 + o0 + j;
            maxY[g] = mx;
            minY[g] = mn;
          }
        }
      }
    }
  }
}

// ---------------------------------------------------------------- BN finalize
__global__ void bn_finalize(const float* __restrict__ st, int cout,
                            const float* __restrict__ gamma,
                            const float* __restrict__ beta,
                            float* __restrict__ scale, float* __restrict__ shift) {
  int o = threadIdx.x;
  if (o >= cout) return;
  float s = 0.0f, q = 0.0f;
  for (int i = 0; i < NSLOT; ++i) {
    s += st[((size_t)i * cout + o) * 2 + 0];
    q += st[((size_t)i * cout + o) * 2 + 1];
  }
  float mean = s * (1.0f / CNT_F);
  float var = q * (1.0f / CNT_F) - mean * mean;
  float sc = gamma[o] / sqrtf(var + 1e-5f);
  scale[o] = sc;
  shift[o] = beta[o] - mean * sc;
}

// ---------------------------------------------------------------- pooling
__global__ __launch_bounds__(256) void pool_kernel(
    const float* __restrict__ maxY, const float* __restrict__ minY,
    const float* __restrict__ bnp, float* __restrict__ out) {
  __shared__ float tile[128 * 65];
  int b = blockIdx.x >> 4;
  int sbase = (blockIdx.x & 15) * 64;
  int t = threadIdx.x;
#pragma unroll 4
  for (int i = 0; i < 32; ++i) {
    int e = i * 256 + t;
    int sl = e >> 7, o = e & 127;
    float sc = bnp[256 + o], sh = bnp[384 + o];
    size_t g = ((size_t)(b * S_ + sbase + sl)) * 128 + o;
    float v = (sc >= 0.0f) ? maxY[g] : minY[g];
    tile[o * 65 + sl] = fmaxf(fmaf(v, sc, sh), 0.0f);
  }
  __syncthreads();
  int sl = t & 63;
  for (int o2 = t >> 6; o2 < 128; o2 += 4) {
    out[((size_t)(b * 128 + o2)) * S_ + sbase + sl] = tile[o2 * 65 + sl];
  }
}

// ---------------------------------------------------------------- launch
static inline size_t alup(size_t x) { return (x + 255) & ~(size_t)255; }

extern "C" void kernel_launch(void* const* d_in, const int* in_sizes, int n_in,
                              void* d_out, int out_size, void* d_ws, size_t ws_size,
                              hipStream_t stream) {
  (void)in_sizes; (void)n_in; (void)out_size;
  const float* xyz = (const float*)d_in[0];
  const float* points = (const float*)d_in[1];
  const float* w0 = (const float*)d_in[2];
  const float* b0 = (const float*)d_in[3];
  const float* g0 = (const float*)d_in[4];
  const float* be0 = (const float*)d_in[5];
  const float* w1 = (const float*)d_in[6];
  const float* b1 = (const float*)d_in[7];
  const float* g1 = (const float*)d_in[8];
  const float* be1 = (const float*)d_in[9];
  const float* w2 = (const float*)d_in[10];
  const float* b2 = (const float*)d_in[11];
  const float* g2 = (const float*)d_in[12];
  const float* be2 = (const float*)d_in[13];
  float* out_newxyz = (float*)d_out;
  float* out_newpts = out_newxyz + (size_t)B_ * S_ * 3;

  // common carve
  char* p = (char*)d_ws;
  int* fps = (int*)p;     p += alup((size_t)B_ * S_ * 4);
  int* nn = (int*)p;      p += alup((size_t)B_ * S_ * K_ * 4);
  float* ptn = (float*)p; p += alup((size_t)B_ * N_ * 4);
  float* st0 = (float*)p; p += (size_t)NSLOT * 64 * 2 * 4;
  float* st1 = (float*)p; p += (size_t)NSLOT * 64 * 2 * 4;
  float* st2 = (float*)p; p += (size_t)NSLOT * 128 * 2 * 4;
  float* bnp = (float*)p; p += alup(512 * 4);
  float* wT0 = (float*)p; p += alup(67 * 64 * 4);
  float* wT1 = (float*)p; p += alup(64 * 64 * 4);
  float* wT2 = (float*)p; p += alup(64 * 128 * 4);
  float* maxY = (float*)p; p += (size_t)B_ * S_ * 128 * 4;
  float* minY = (float*)p; p += (size_t)B_ * S_ * 128 * 4;
  char* p_common = p;
  // FULL extras: y0T, y1T (bf16, transposed [c][row])
  ushort_t* y0T = (ushort_t*)p; 
  ushort_t* y1T = (ushort_t*)(p + (size_t)64 * RWS * 2);
  size_t need_full = (size_t)(p_common - (char*)d_ws) + 2ull * 64 * RWS * 2;
  size_t need_legacy = (size_t)(p_common - (char*)d_ws);
  bool full = need_full <= ws_size;
  if (!full && need_legacy > ws_size) return;  // visible failure

  float* sc0 = bnp;       float* sh0 = bnp + 64;
  float* sc1 = bnp + 128; float* sh1 = bnp + 192;
  float* sc2 = bnp + 256; float* sh2 = bnp + 384;

  hipMemsetAsync(st0, 0, (size_t)NSLOT * (64 + 64 + 128) * 2 * 4, stream);
  prep_wT<<<32, 256, 0, stream>>>(w0, w1, w2, wT0, wT1, wT2);
  ptnorm_kernel<<<(B_ * N_) / 256, 256, 0, stream>>>(xyz, ptn);
  fps_kernel<<<B_, FPS_T, 0, stream>>>(xyz, fps, out_newxyz);
  knn_kernel<<<B_ * S_, 64, 0, stream>>>(xyz, ptn, out_newxyz, fps, nn);
  if (full) {
    gemm0_mat<<<(B_ * S_) / 2, 64, 0, stream>>>(
        xyz, points, out_newxyz, nn, wT0, b0, y0T, st0);
    bn_finalize<<<1, 128, 0, stream>>>(st0, 64, g0, be0, sc0, sh0);
    gemm1_mat<<<(B_ * S_) / 2, 64, 0, stream>>>(y0T, bnp, wT1, b1, y1T, st1);
    bn_finalize<<<1, 128, 0, stream>>>(st1, 64, g1, be1, sc1, sh1);
    gemm2_mat<<<(B_ * S_) / 2, 64, 0, stream>>>(y1T, bnp, wT2, b2, st2, maxY, minY);
    bn_finalize<<<1, 128, 0, stream>>>(st2, 128, g2, be2, sc2, sh2);
  } else {
    fused_layers<0><<<(B_ * S_) / 2, 64, 0, stream>>>(
        xyz, points, out_newxyz, nn, wT0, b0, wT1, b1, wT2, b2, bnp, st0, maxY, minY);
    bn_finalize<<<1, 128, 0, stream>>>(st0, 64, g0, be0, sc0, sh0);
    fused_layers<1><<<(B_ * S_) / 2, 64, 0, stream>>>(
        xyz, points, out_newxyz, nn, wT0, b0, wT1, b1, wT2, b2, bnp, st1, maxY, minY);
    bn_finalize<<<1, 128, 0, stream>>>(st1, 64, g1, be1, sc1, sh1);
    fused_layers<2><<<(B_ * S_) / 2, 64, 0, stream>>>(
        xyz, points, out_newxyz, nn, wT0, b0, wT1, b1, wT2, b2, bnp, st2, maxY, minY);
    bn_finalize<<<1, 128, 0, stream>>>(st2, 128, g2, be2, sc2, sh2);
  }
  pool_kernel<<<B_ * (S_ / 64), 256, 0, stream>>>(maxY, minY, bnp, out_newpts);
}

// Round 10
// 1599.433 us; speedup vs baseline: 1.5813x; 1.0688x over previous
//
#include <hip/hip_runtime.h>

#define B_ 16
#define N_ 4096
#define S_ 1024
#define K_ 32
#define NSLOT 128
#define CNT_F 524288.0f   // B*S*K
#define RWS 524288        // total rows = B*S*K

typedef unsigned short ushort_t;

__device__ __forceinline__ ushort_t f2bf(float f) {
  unsigned u = __float_as_uint(f);
  unsigned r = (u + 0x7fffu + ((u >> 16) & 1u)) >> 16;
  return (ushort_t)r;
}

// ---------------------------------------------------------------- FPS
// 256 threads (4 waves): same dist-loop wall as 512 (1 wave/SIMD), but half
// the barrier participants and half the exchange keys -> shorter serial tail.
#define FPS_T 256
#define FPS_P (N_ / FPS_T)
#define FPS_W (FPS_T / 64)

template <int CTRL>
__device__ __forceinline__ void dpp_max_u64(unsigned& hi, unsigned& lo) {
  unsigned h2 = (unsigned)__builtin_amdgcn_update_dpp(0, (int)hi, CTRL, 0xf, 0xf, true);
  unsigned l2 = (unsigned)__builtin_amdgcn_update_dpp(0, (int)lo, CTRL, 0xf, 0xf, true);
  bool take = (h2 > hi) || (h2 == hi && l2 > lo);
  hi = take ? h2 : hi;
  lo = take ? l2 : lo;
}

__global__ __launch_bounds__(FPS_T) void fps_kernel(
    const float* __restrict__ xyz, int* __restrict__ fps_idx,
    float* __restrict__ out_newxyz) {
  __shared__ float xyz_s[N_ * 3];
  __shared__ int idx_s[S_];
  __shared__ unsigned long long keys_s[2][FPS_W];
  int b = blockIdx.x, t = threadIdx.x;
  const float* xb = xyz + (size_t)b * N_ * 3;
  for (int i = t; i < N_ * 3; i += FPS_T) xyz_s[i] = xb[i];
  __syncthreads();
  float px[FPS_P], py[FPS_P], pz[FPS_P], dd[FPS_P];
#pragma unroll
  for (int j = 0; j < FPS_P; ++j) {
    int n = t + j * FPS_T;
    px[j] = xyz_s[n * 3 + 0];
    py[j] = xyz_s[n * 3 + 1];
    pz[j] = xyz_s[n * 3 + 2];
    dd[j] = 1e10f;
  }
  int fi = 0;
#pragma unroll 1
  for (int s = 0; s < S_; ++s) {
    if (t == 0) idx_s[s] = fi;
    float cx = xyz_s[fi * 3 + 0], cy = xyz_s[fi * 3 + 1], cz = xyz_s[fi * 3 + 2];
    float bv = -1.0f;
    int bi = 0;
#pragma unroll
    for (int j = 0; j < FPS_P; ++j) {
      float dx = __fsub_rn(px[j], cx);
      float dy = __fsub_rn(py[j], cy);
      float dz = __fsub_rn(pz[j], cz);
      float d = __fadd_rn(__fadd_rn(__fmul_rn(dx, dx), __fmul_rn(dy, dy)),
                          __fmul_rn(dz, dz));
      d = fminf(dd[j], d);
      dd[j] = d;
      if (d > bv) { bv = d; bi = t + j * FPS_T; }
    }
    unsigned hi = __float_as_uint(bv);
    unsigned lo = (unsigned)(N_ - 1 - bi);
    dpp_max_u64<0x111>(hi, lo);
    dpp_max_u64<0x112>(hi, lo);
    dpp_max_u64<0x114>(hi, lo);
    dpp_max_u64<0x118>(hi, lo);
    dpp_max_u64<0x142>(hi, lo);
    dpp_max_u64<0x143>(hi, lo);
    unsigned whi = (unsigned)__builtin_amdgcn_readlane((int)hi, 63);
    unsigned wlo = (unsigned)__builtin_amdgcn_readlane((int)lo, 63);
    if ((t & 63) == 0)
      keys_s[s & 1][t >> 6] = ((unsigned long long)whi << 32) | wlo;
    __syncthreads();
    unsigned long long m = keys_s[s & 1][0];
#pragma unroll
    for (int w = 1; w < FPS_W; ++w) {
      unsigned long long k = keys_s[s & 1][w];
      m = k > m ? k : m;
    }
    fi = (N_ - 1) - (int)(unsigned)(m & 0xFFFFFFFFULL);
  }
  __syncthreads();
  for (int s = t; s < S_; s += FPS_T) {
    int i = idx_s[s];
    fps_idx[b * S_ + s] = i;
    out_newxyz[((size_t)b * S_ + s) * 3 + 0] = xyz_s[i * 3 + 0];
    out_newxyz[((size_t)b * S_ + s) * 3 + 1] = xyz_s[i * 3 + 1];
    out_newxyz[((size_t)b * S_ + s) * 3 + 2] = xyz_s[i * 3 + 2];
  }
}

// ---------------------------------------------------------------- point norms
__global__ void ptnorm_kernel(const float* __restrict__ xyz, float* __restrict__ pt) {
  int i = blockIdx.x * 256 + threadIdx.x;
  float x = xyz[(size_t)i * 3 + 0];
  float y = xyz[(size_t)i * 3 + 1];
  float z = xyz[(size_t)i * 3 + 2];
  pt[i] = __fadd_rn(__fadd_rn(__fmul_rn(x, x), __fmul_rn(y, y)), __fmul_rn(z, z));
}

// ---------------------------------------------------------------- kNN (K=32)
__global__ __launch_bounds__(64) void knn_kernel(
    const float* __restrict__ xyz, const float* __restrict__ ptnorm,
    const float* __restrict__ newxyz, const int* __restrict__ fps_idx,
    int* __restrict__ nn_idx) {
  int bs = blockIdx.x;
  int b = bs >> 10;
  int lane = threadIdx.x;
  float sx = newxyz[(size_t)bs * 3 + 0];
  float sy = newxyz[(size_t)bs * 3 + 1];
  float sz = newxyz[(size_t)bs * 3 + 2];
  int fi = fps_idx[bs];
  float nxn = ptnorm[(size_t)b * N_ + fi];
  const float* xb = xyz + (size_t)b * N_ * 3;
  const float* pnb = ptnorm + (size_t)b * N_;
  unsigned u[64];
#pragma unroll
  for (int j = 0; j < 64; ++j) {
    int n = j * 64 + lane;
    float x = xb[n * 3 + 0], y = xb[n * 3 + 1], z = xb[n * 3 + 2];
    float e = __fadd_rn(__fadd_rn(__fmul_rn(sx, x), __fmul_rn(sy, y)),
                        __fmul_rn(sz, z));
    float d = __fadd_rn(__fadd_rn(nxn, pnb[n]), __fmul_rn(-2.0f, e));
    int sb = __float_as_int(d);
    u[j] = (sb < 0) ? ~((unsigned)sb) : (((unsigned)sb) | 0x80000000u);
  }
  unsigned keep = 0;
#pragma unroll 1
  for (int p = 0; p < K_; ++p) {
    unsigned bv = 0xFFFFFFFFu;
    int bj = 0;
#pragma unroll
    for (int j = 0; j < 64; ++j) {
      if (u[j] < bv) { bv = u[j]; bj = j; }
    }
    unsigned bn = (unsigned)(bj * 64 + lane);
#pragma unroll
    for (int off = 32; off > 0; off >>= 1) {
      unsigned ov = __shfl_down(bv, off);
      unsigned on = __shfl_down(bn, off);
      if (ov < bv || (ov == bv && on < bn)) { bv = ov; bn = on; }
    }
    unsigned gn = __shfl(bn, 0);
    if (lane == p) keep = gn;
    if ((gn & 63u) == (unsigned)lane) {
      int gj = gn >> 6;
#pragma unroll
      for (int j = 0; j < 64; ++j)
        if (j == gj) u[j] = 0xFFFFFFFFu;
    }
  }
  if (lane < K_) nn_idx[(size_t)bs * K_ + lane] = (int)keep;
}

// ---------------------------------------------------------------- weight transpose
__global__ void prep_wT(const float* __restrict__ w0, const float* __restrict__ w1,
                        const float* __restrict__ w2, float* __restrict__ wT0,
                        float* __restrict__ wT1, float* __restrict__ wT2) {
  int t = blockIdx.x * 256 + threadIdx.x;
  if (t < 64 * 67) { int o = t / 67, c = t % 67; wT0[c * 64 + o] = w0[t]; }
  if (t < 64 * 64) { int o = t >> 6, c = t & 63; wT1[c * 64 + o] = w1[t]; }
  if (t < 128 * 64) { int o = t >> 6, c = t & 63; wT2[c * 128 + o] = w2[t]; }
}

// ---------------------------------------------------------------- stats helper
__device__ __forceinline__ void stats_accum(float acc[8][8], const float* __restrict__ bias_,
                                            int obase, int o0, int mq,
                                            float* __restrict__ stp) {
#pragma unroll
  for (int j = 0; j < 8; ++j) {
    float bv = bias_[obase + o0 + j];
    float s = 0.0f, q = 0.0f;
#pragma unroll
    for (int i = 0; i < 8; ++i) {
      float ya = acc[i][j] + bv;
      s += ya;
      q = fmaf(ya, ya, q);
    }
#pragma unroll
    for (int off = 1; off < 8; off <<= 1) {
      s += __shfl_xor(s, off);
      q += __shfl_xor(q, off);
    }
    if (mq == 0) {
      atomicAdd(&stp[(size_t)(obase + o0 + j) * 2 + 0], s);
      atomicAdd(&stp[(size_t)(obase + o0 + j) * 2 + 1], q);
    }
  }
}

// ================================================================ FULL path
// Phase A: 256 threads = 4 waves, each wave owns one 64-row tile (4 tiles of
// LDS, conflict-free lane=row gather). GEMM0, store y0 bf16 [c][row], stats0.
__global__ __launch_bounds__(256) void gemm0_mat(
    const float* __restrict__ xyz, const float* __restrict__ points,
    const float* __restrict__ newxyz, const int* __restrict__ nn_idx,
    const float* __restrict__ wT0, const float* __restrict__ bias0,
    ushort_t* __restrict__ y0T, float* __restrict__ stats) {
  constexpr int MP = 68;
  __shared__ __align__(16) float xs[4][67 * MP];
  int t = threadIdx.x;
  int blk = blockIdx.x;
  int g = t >> 6, l = t & 63;
  int r = blk * 256 + t;          // global row
  int b = r >> 15;                // 32768 rows per batch
  int sg = r >> 5;                // global s index (32 rows per s)
  int idx = nn_idx[r];
  const float* xb = xyz + (size_t)b * N_ * 3;
  const float4* pb4 = reinterpret_cast<const float4*>(
      points + (size_t)b * N_ * 64 + (size_t)idx * 64);
  float nx0 = newxyz[(size_t)sg * 3 + 0];
  float nx1 = newxyz[(size_t)sg * 3 + 1];
  float nx2 = newxyz[(size_t)sg * 3 + 2];
  float* xsg = xs[g];
#pragma unroll
  for (int q = 0; q < 16; ++q) {
    float4 v = pb4[q];
    xsg[(3 + 4 * q + 0) * MP + l] = v.x;
    xsg[(3 + 4 * q + 1) * MP + l] = v.y;
    xsg[(3 + 4 * q + 2) * MP + l] = v.z;
    xsg[(3 + 4 * q + 3) * MP + l] = v.w;
  }
  xsg[0 * MP + l] = __fsub_rn(xb[idx * 3 + 0], nx0);
  xsg[1 * MP + l] = __fsub_rn(xb[idx * 3 + 1], nx1);
  xsg[2 * MP + l] = __fsub_rn(xb[idx * 3 + 2], nx2);
  __syncthreads();
  int mq = l & 7, oq = l >> 3;
  int m0 = mq * 8, o0 = oq * 8;
  int row0 = blk * 256 + g * 64;
  float acc[8][8];
#pragma unroll
  for (int i = 0; i < 8; ++i)
#pragma unroll
    for (int j = 0; j < 8; ++j) acc[i][j] = 0.0f;
#pragma unroll 2
  for (int c = 0; c < 67; ++c) {
    float4 xa = *reinterpret_cast<const float4*>(&xsg[c * MP + m0]);
    float4 xb4 = *reinterpret_cast<const float4*>(&xsg[c * MP + m0 + 4]);
    float4 wa = *reinterpret_cast<const float4*>(&wT0[c * 64 + o0]);
    float4 wb = *reinterpret_cast<const float4*>(&wT0[c * 64 + o0 + 4]);
    float xr[8] = {xa.x, xa.y, xa.z, xa.w, xb4.x, xb4.y, xb4.z, xb4.w};
    float wr[8] = {wa.x, wa.y, wa.z, wa.w, wb.x, wb.y, wb.z, wb.w};
#pragma unroll
    for (int i = 0; i < 8; ++i)
#pragma unroll
      for (int j = 0; j < 8; ++j) acc[i][j] = fmaf(xr[i], wr[j], acc[i][j]);
  }
  ushort_t* yo = y0T + row0 + m0;
#pragma unroll
  for (int j = 0; j < 8; ++j) {
    float bv = bias0[o0 + j];
    unsigned pk[4];
#pragma unroll
    for (int ii = 0; ii < 4; ++ii) {
      float a = acc[2 * ii][j] + bv;
      float c2 = acc[2 * ii + 1][j] + bv;
      pk[ii] = (unsigned)f2bf(a) | ((unsigned)f2bf(c2) << 16);
    }
    *reinterpret_cast<uint4*>(yo + (size_t)(o0 + j) * RWS) =
        make_uint4(pk[0], pk[1], pk[2], pk[3]);
  }
  stats_accum(acc, bias0, 0, o0, mq, stats + (size_t)(blk & (NSLOT - 1)) * 64 * 2);
}

// Phase B: 256 threads = 4 row-groups, LDS-free. Stream y0T, bn0/relu inline,
// GEMM1, store y1T bf16, stats1.
__global__ __launch_bounds__(256) void gemm1_mat(
    const ushort_t* __restrict__ y0T, const float* __restrict__ bnp,
    const float* __restrict__ wT1, const float* __restrict__ bias1,
    ushort_t* __restrict__ y1T, float* __restrict__ stats) {
  int t = threadIdx.x;
  int blk = blockIdx.x;
  int g = t >> 6, l = t & 63;
  int row0 = blk * 256 + g * 64;
  int mq = l & 7, oq = l >> 3;
  int m0 = mq * 8, o0 = oq * 8;
  float acc[8][8];
#pragma unroll
  for (int i = 0; i < 8; ++i)
#pragma unroll
    for (int j = 0; j < 8; ++j) acc[i][j] = 0.0f;
  const ushort_t* xbase = y0T + row0 + m0;
#pragma unroll 2
  for (int c = 0; c < 64; ++c) {
    uint4 xv = *reinterpret_cast<const uint4*>(xbase + (size_t)c * RWS);
    float sc = bnp[c], sh = bnp[64 + c];
    float xr[8];
    xr[0] = __uint_as_float(xv.x << 16);
    xr[1] = __uint_as_float(xv.x & 0xffff0000u);
    xr[2] = __uint_as_float(xv.y << 16);
    xr[3] = __uint_as_float(xv.y & 0xffff0000u);
    xr[4] = __uint_as_float(xv.z << 16);
    xr[5] = __uint_as_float(xv.z & 0xffff0000u);
    xr[6] = __uint_as_float(xv.w << 16);
    xr[7] = __uint_as_float(xv.w & 0xffff0000u);
#pragma unroll
    for (int i = 0; i < 8; ++i) xr[i] = fmaxf(fmaf(xr[i], sc, sh), 0.0f);
    float4 wa = *reinterpret_cast<const float4*>(&wT1[c * 64 + o0]);
    float4 wb = *reinterpret_cast<const float4*>(&wT1[c * 64 + o0 + 4]);
    float wr[8] = {wa.x, wa.y, wa.z, wa.w, wb.x, wb.y, wb.z, wb.w};
#pragma unroll
    for (int i = 0; i < 8; ++i)
#pragma unroll
      for (int j = 0; j < 8; ++j) acc[i][j] = fmaf(xr[i], wr[j], acc[i][j]);
  }
  ushort_t* yo = y1T + row0 + m0;
#pragma unroll
  for (int j = 0; j < 8; ++j) {
    float bv = bias1[o0 + j];
    unsigned pk[4];
#pragma unroll
    for (int ii = 0; ii < 4; ++ii) {
      float a = acc[2 * ii][j] + bv;
      float c2 = acc[2 * ii + 1][j] + bv;
      pk[ii] = (unsigned)f2bf(a) | ((unsigned)f2bf(c2) << 16);
    }
    *reinterpret_cast<uint4*>(yo + (size_t)(o0 + j) * RWS) =
        make_uint4(pk[0], pk[1], pk[2], pk[3]);
  }
  stats_accum(acc, bias1, 0, o0, mq, stats + (size_t)(blk & (NSLOT - 1)) * 64 * 2);
}

// Phase C: 256 threads = 4 row-groups, LDS-free. Stream y1T, bn1/relu inline,
// GEMM2 (2 halves), stats2 + min/max.
__global__ __launch_bounds__(256) void gemm2_mat(
    const ushort_t* __restrict__ y1T, const float* __restrict__ bnp,
    const float* __restrict__ wT2, const float* __restrict__ bias2,
    float* __restrict__ stats, float* __restrict__ maxY, float* __restrict__ minY) {
  int t = threadIdx.x;
  int blk = blockIdx.x;
  int g = t >> 6, l = t & 63;
  int row0 = blk * 256 + g * 64;
  int bs0 = row0 >> 5;  // global s of this group's first row (2 s per group)
  int mq = l & 7, oq = l >> 3;
  int m0 = mq * 8, o0 = oq * 8;
  const ushort_t* xbase = y1T + row0 + m0;
  float* stp = stats + (size_t)(blk & (NSLOT - 1)) * 128 * 2;
#pragma unroll 1
  for (int h = 0; h < 2; ++h) {
    float acc[8][8];
#pragma unroll
    for (int i = 0; i < 8; ++i)
#pragma unroll
      for (int j = 0; j < 8; ++j) acc[i][j] = 0.0f;
#pragma unroll 2
    for (int c = 0; c < 64; ++c) {
      uint4 xv = *reinterpret_cast<const uint4*>(xbase + (size_t)c * RWS);
      float sc = bnp[128 + c], sh = bnp[192 + c];
      float xr[8];
      xr[0] = __uint_as_float(xv.x << 16);
      xr[1] = __uint_as_float(xv.x & 0xffff0000u);
      xr[2] = __uint_as_float(xv.y << 16);
      xr[3] = __uint_as_float(xv.y & 0xffff0000u);
      xr[4] = __uint_as_float(xv.z << 16);
      xr[5] = __uint_as_float(xv.z & 0xffff0000u);
      xr[6] = __uint_as_float(xv.w << 16);
      xr[7] = __uint_as_float(xv.w & 0xffff0000u);
#pragma unroll
      for (int i = 0; i < 8; ++i) xr[i] = fmaxf(fmaf(xr[i], sc, sh), 0.0f);
      float4 wa = *reinterpret_cast<const float4*>(&wT2[c * 128 + h * 64 + o0]);
      float4 wb = *reinterpret_cast<const float4*>(&wT2[c * 128 + h * 64 + o0 + 4]);
      float wr[8] = {wa.x, wa.y, wa.z, wa.w, wb.x, wb.y, wb.z, wb.w};
#pragma unroll
      for (int i = 0; i < 8; ++i)
#pragma unroll
        for (int j = 0; j < 8; ++j) acc[i][j] = fmaf(xr[i], wr[j], acc[i][j]);
    }
    stats_accum(acc, bias2, h * 64, o0, mq, stp);
#pragma unroll
    for (int j = 0; j < 8; ++j) {
      float bv = bias2[h * 64 + o0 + j];
      float mx = -3.4e38f, mn = 3.4e38f;
#pragma unroll
      for (int i = 0; i < 8; ++i) {
        float ya = acc[i][j] + bv;
        mx = fmaxf(mx, ya);
        mn = fminf(mn, ya);
      }
      mx = fmaxf(mx, __shfl_xor(mx, 1));
      mn = fminf(mn, __shfl_xor(mn, 1));
      mx = fmaxf(mx, __shfl_xor(mx, 2));
      mn = fminf(mn, __shfl_xor(mn, 2));
      if ((mq & 3) == 0) {
        size_t gidx = ((size_t)(bs0 + (mq >> 2))) * 128 + h * 64 + o0 + j;
        maxY[gidx] = mx;
        minY[gidx] = mn;
      }
    }
  }
}

// ================================================================ legacy path
template <int PHASE>
__global__ __launch_bounds__(64) void fused_layers(
    const float* __restrict__ xyz, const float* __restrict__ points,
    const float* __restrict__ newxyz, const int* __restrict__ nn_idx,
    const float* __restrict__ wT0, const float* __restrict__ bias0,
    const float* __restrict__ wT1, const float* __restrict__ bias1,
    const float* __restrict__ wT2, const float* __restrict__ bias2,
    const float* __restrict__ bnp,
    float* __restrict__ stats, float* __restrict__ maxY, float* __restrict__ minY) {
  constexpr int MP = 68;
  __shared__ __align__(16) float xs[67 * MP];
  __shared__ int nn_s[64];
  __shared__ float nx_s[6];
  int t = threadIdx.x;
  int blk = blockIdx.x;
  int row0 = blk * 64;
  int b = blk >> 9;
  int s0 = (blk & 511) * 2;
  int bs0 = b * S_ + s0;
  nn_s[t] = nn_idx[row0 + t];
  if (t < 6) nx_s[t] = newxyz[(size_t)bs0 * 3 + t];
  __syncthreads();
  const float* xb = xyz + (size_t)b * N_ * 3;
  const float* pb = points + (size_t)b * N_ * 64;
#pragma unroll 4
  for (int m = 0; m < 64; ++m) {
    int idx = nn_s[m];
    if (t < 3) {
      xs[t * MP + m] = __fsub_rn(xb[idx * 3 + t], nx_s[(m >> 5) * 3 + t]);
      xs[(64 + t) * MP + m] = pb[(size_t)idx * 64 + 61 + t];
    } else {
      xs[t * MP + m] = pb[(size_t)idx * 64 + (t - 3)];
    }
  }
  __syncthreads();
  int mq = t & 7, oq = t >> 3;
  int m0 = mq * 8, o0 = oq * 8;
  float acc[8][8];
#pragma unroll
  for (int i = 0; i < 8; ++i)
#pragma unroll
    for (int j = 0; j < 8; ++j) acc[i][j] = 0.0f;
#pragma unroll 2
  for (int c = 0; c < 67; ++c) {
    float4 xa = *reinterpret_cast<const float4*>(&xs[c * MP + m0]);
    float4 xb4 = *reinterpret_cast<const float4*>(&xs[c * MP + m0 + 4]);
    float4 wa = *reinterpret_cast<const float4*>(&wT0[c * 64 + o0]);
    float4 wb = *reinterpret_cast<const float4*>(&wT0[c * 64 + o0 + 4]);
    float xr[8] = {xa.x, xa.y, xa.z, xa.w, xb4.x, xb4.y, xb4.z, xb4.w};
    float wr[8] = {wa.x, wa.y, wa.z, wa.w, wb.x, wb.y, wb.z, wb.w};
#pragma unroll
    for (int i = 0; i < 8; ++i)
#pragma unroll
      for (int j = 0; j < 8; ++j) acc[i][j] = fmaf(xr[i], wr[j], acc[i][j]);
  }
  if constexpr (PHASE == 0) {
    stats_accum(acc, bias0, 0, o0, mq, stats + (size_t)(blk & (NSLOT - 1)) * 64 * 2);
    return;
  } else {
    __syncthreads();
#pragma unroll
    for (int j = 0; j < 8; ++j) {
      float bv = bias0[o0 + j];
      float sc = bnp[o0 + j], sh = bnp[64 + o0 + j];
#pragma unroll
      for (int i = 0; i < 8; ++i) {
        float ya = acc[i][j] + bv;
        xs[(o0 + j) * MP + (m0 + i)] = fmaxf(fmaf(ya, sc, sh), 0.0f);
      }
    }
    __syncthreads();
#pragma unroll
    for (int i = 0; i < 8; ++i)
#pragma unroll
      for (int j = 0; j < 8; ++j) acc[i][j] = 0.0f;
#pragma unroll 2
    for (int c = 0; c < 64; ++c) {
      float4 xa = *reinterpret_cast<const float4*>(&xs[c * MP + m0]);
      float4 xb4 = *reinterpret_cast<const float4*>(&xs[c * MP + m0 + 4]);
      float4 wa = *reinterpret_cast<const float4*>(&wT1[c * 64 + o0]);
      float4 wb = *reinterpret_cast<const float4*>(&wT1[c * 64 + o0 + 4]);
      float xr[8] = {xa.x, xa.y, xa.z, xa.w, xb4.x, xb4.y, xb4.z, xb4.w};
      float wr[8] = {wa.x, wa.y, wa.z, wa.w, wb.x, wb.y, wb.z, wb.w};
#pragma unroll
      for (int i = 0; i < 8; ++i)
#pragma unroll
        for (int j = 0; j < 8; ++j) acc[i][j] = fmaf(xr[i], wr[j], acc[i][j]);
    }
    if constexpr (PHASE == 1) {
      stats_accum(acc, bias1, 0, o0, mq, stats + (size_t)(blk & (NSLOT - 1)) * 64 * 2);
      return;
    } else {
      __syncthreads();
#pragma unroll
      for (int j = 0; j < 8; ++j) {
        float bv = bias1[o0 + j];
        float sc = bnp[128 + o0 + j], sh = bnp[192 + o0 + j];
#pragma unroll
        for (int i = 0; i < 8; ++i) {
          float ya = acc[i][j] + bv;
          xs[(o0 + j) * MP + (m0 + i)] = fmaxf(fmaf(ya, sc, sh), 0.0f);
        }
      }
      __syncthreads();
      float* stp = stats + (size_t)(blk & (NSLOT - 1)) * 128 * 2;
#pragma unroll 1
      for (int h = 0; h < 2; ++h) {
#pragma unroll
        for (int i = 0; i < 8; ++i)
#pragma unroll
          for (int j = 0; j < 8; ++j) acc[i][j] = 0.0f;
#pragma unroll 2
        for (int c = 0; c < 64; ++c) {
          float4 xa = *reinterpret_cast<const float4*>(&xs[c * MP + m0]);
          float4 xb4 = *reinterpret_cast<const float4*>(&xs[c * MP + m0 + 4]);
          float4 wa = *reinterpret_cast<const float4*>(&wT2[c * 128 + h * 64 + o0]);
          float4 wb = *reinterpret_cast<const float4*>(&wT2[c * 128 + h * 64 + o0 + 4]);
          float xr[8] = {xa.x, xa.y, xa.z, xa.w, xb4.x, xb4.y, xb4.z, xb4.w};
          float wr[8] = {wa.x, wa.y, wa.z, wa.w, wb.x, wb.y, wb.z, wb.w};
#pragma unroll
          for (int i = 0; i < 8; ++i)
#pragma unroll
            for (int j = 0; j < 8; ++j) acc[i][j] = fmaf(xr[i], wr[j], acc[i][j]);
        }
        stats_accum(acc, bias2, h * 64, o0, mq, stp);
#pragma unroll
        for (int j = 0; j < 8; ++j) {
          float bv = bias2[h * 64 + o0 + j];
          float mx = -3.4e38f, mn = 3.4e38f;
#pragma unroll
          for (int i = 0; i < 8; ++i) {
            float ya = acc[i][j] + bv;
            mx = fmaxf(mx, ya);
            mn = fminf(mn, ya);
          }
          mx = fmaxf(mx, __shfl_xor(mx, 1));
          mn = fminf(mn, __shfl_xor(mn, 1));
          mx = fmaxf(mx, __shfl_xor(mx, 2));
          mn = fminf(mn, __shfl_xor(mn, 2));
          if ((mq & 3) == 0) {
            size_t g = ((size_t)(bs0 + (mq >> 2))) * 128 + h * 64 + o0 + j;
            maxY[g] = mx;
            minY[g] = mn;
          }
        }
      }
    }
  }
}

// ---------------------------------------------------------------- BN finalize
__global__ void bn_finalize(const float* __restrict__ st, int cout,
                            const float* __restrict__ gamma,
                            const float* __restrict__ beta,
                            float* __restrict__ scale, float* __restrict__ shift) {
  int o = threadIdx.x;
  if (o >= cout) return;
  float s = 0.0f, q = 0.0f;
  for (int i = 0; i < NSLOT; ++i) {
    s += st[((size_t)i * cout + o) * 2 + 0];
    q += st[((size_t)i * cout + o) * 2 + 1];
  }
  float mean = s * (1.0f / CNT_F);
  float var = q * (1.0f / CNT_F) - mean * mean;
  float sc = gamma[o] / sqrtf(var + 1e-5f);
  scale[o] = sc;
  shift[o] = beta[o] - mean * sc;
}

// ---------------------------------------------------------------- pooling
__global__ __launch_bounds__(256) void pool_kernel(
    const float* __restrict__ maxY, const float* __restrict__ minY,
    const float* __restrict__ bnp, float* __restrict__ out) {
  __shared__ float tile[128 * 65];
  int b = blockIdx.x >> 4;
  int sbase = (blockIdx.x & 15) * 64;
  int t = threadIdx.x;
#pragma unroll 4
  for (int i = 0; i < 32; ++i) {
    int e = i * 256 + t;
    int sl = e >> 7, o = e & 127;
    float sc = bnp[256 + o], sh = bnp[384 + o];
    size_t g = ((size_t)(b * S_ + sbase + sl)) * 128 + o;
    float v = (sc >= 0.0f) ? maxY[g] : minY[g];
    tile[o * 65 + sl] = fmaxf(fmaf(v, sc, sh), 0.0f);
  }
  __syncthreads();
  int sl = t & 63;
  for (int o2 = t >> 6; o2 < 128; o2 += 4) {
    out[((size_t)(b * 128 + o2)) * S_ + sbase + sl] = tile[o2 * 65 + sl];
  }
}

// ---------------------------------------------------------------- launch
static inline size_t alup(size_t x) { return (x + 255) & ~(size_t)255; }

extern "C" void kernel_launch(void* const* d_in, const int* in_sizes, int n_in,
                              void* d_out, int out_size, void* d_ws, size_t ws_size,
                              hipStream_t stream) {
  (void)in_sizes; (void)n_in; (void)out_size;
  const float* xyz = (const float*)d_in[0];
  const float* points = (const float*)d_in[1];
  const float* w0 = (const float*)d_in[2];
  const float* b0 = (const float*)d_in[3];
  const float* g0 = (const float*)d_in[4];
  const float* be0 = (const float*)d_in[5];
  const float* w1 = (const float*)d_in[6];
  const float* b1 = (const float*)d_in[7];
  const float* g1 = (const float*)d_in[8];
  const float* be1 = (const float*)d_in[9];
  const float* w2 = (const float*)d_in[10];
  const float* b2 = (const float*)d_in[11];
  const float* g2 = (const float*)d_in[12];
  const float* be2 = (const float*)d_in[13];
  float* out_newxyz = (float*)d_out;
  float* out_newpts = out_newxyz + (size_t)B_ * S_ * 3;

  char* p = (char*)d_ws;
  int* fps = (int*)p;     p += alup((size_t)B_ * S_ * 4);
  int* nn = (int*)p;      p += alup((size_t)B_ * S_ * K_ * 4);
  float* ptn = (float*)p; p += alup((size_t)B_ * N_ * 4);
  float* st0 = (float*)p; p += (size_t)NSLOT * 64 * 2 * 4;
  float* st1 = (float*)p; p += (size_t)NSLOT * 64 * 2 * 4;
  float* st2 = (float*)p; p += (size_t)NSLOT * 128 * 2 * 4;
  float* bnp = (float*)p; p += alup(512 * 4);
  float* wT0 = (float*)p; p += alup(67 * 64 * 4);
  float* wT1 = (float*)p; p += alup(64 * 64 * 4);
  float* wT2 = (float*)p; p += alup(64 * 128 * 4);
  float* maxY = (float*)p; p += (size_t)B_ * S_ * 128 * 4;
  float* minY = (float*)p; p += (size_t)B_ * S_ * 128 * 4;
  char* p_common = p;
  ushort_t* y0T = (ushort_t*)p;
  ushort_t* y1T = (ushort_t*)(p + (size_t)64 * RWS * 2);
  size_t need_full = (size_t)(p_common - (char*)d_ws) + 2ull * 64 * RWS * 2;
  size_t need_legacy = (size_t)(p_common - (char*)d_ws);
  bool full = need_full <= ws_size;
  if (!full && need_legacy > ws_size) return;

  float* sc0 = bnp;       float* sh0 = bnp + 64;
  float* sc1 = bnp + 128; float* sh1 = bnp + 192;
  float* sc2 = bnp + 256; float* sh2 = bnp + 384;

  hipMemsetAsync(st0, 0, (size_t)NSLOT * (64 + 64 + 128) * 2 * 4, stream);
  prep_wT<<<32, 256, 0, stream>>>(w0, w1, w2, wT0, wT1, wT2);
  ptnorm_kernel<<<(B_ * N_) / 256, 256, 0, stream>>>(xyz, ptn);
  fps_kernel<<<B_, FPS_T, 0, stream>>>(xyz, fps, out_newxyz);
  knn_kernel<<<B_ * S_, 64, 0, stream>>>(xyz, ptn, out_newxyz, fps, nn);
  if (full) {
    gemm0_mat<<<(B_ * S_ * K_) / 256, 256, 0, stream>>>(
        xyz, points, out_newxyz, nn, wT0, b0, y0T, st0);
    bn_finalize<<<1, 128, 0, stream>>>(st0, 64, g0, be0, sc0, sh0);
    gemm1_mat<<<(B_ * S_ * K_) / 256, 256, 0, stream>>>(y0T, bnp, wT1, b1, y1T, st1);
    bn_finalize<<<1, 128, 0, stream>>>(st1, 64, g1, be1, sc1, sh1);
    gemm2_mat<<<(B_ * S_ * K_) / 256, 256, 0, stream>>>(y1T, bnp, wT2, b2, st2, maxY, minY);
    bn_finalize<<<1, 128, 0, stream>>>(st2, 128, g2, be2, sc2, sh2);
  } else {
    fused_layers<0><<<(B_ * S_) / 2, 64, 0, stream>>>(
        xyz, points, out_newxyz, nn, wT0, b0, wT1, b1, wT2, b2, bnp, st0, maxY, minY);
    bn_finalize<<<1, 128, 0, stream>>>(st0, 64, g0, be0, sc0, sh0);
    fused_layers<1><<<(B_ * S_) / 2, 64, 0, stream>>>(
        xyz, points, out_newxyz, nn, wT0, b0, wT1, b1, wT2, b2, bnp, st1, maxY, minY);
    bn_finalize<<<1, 128, 0, stream>>>(st1, 64, g1, be1, sc1, sh1);
    fused_layers<2><<<(B_ * S_) / 2, 64, 0, stream>>>(
        xyz, points, out_newxyz, nn, wT0, b0, wT1, b1, wT2, b2, bnp, st2, maxY, minY);
    bn_finalize<<<1, 128, 0, stream>>>(st2, 128, g2, be2, sc2, sh2);
  }
  pool_kernel<<<B_ * (S_ / 64), 256, 0, stream>>>(maxY, minY, bnp, out_newpts);
}